// Round 2
// baseline (696.533 us; speedup 1.0000x reference)
//
#include <hip/hip_runtime.h>
#include <stdint.h>

#define BATCH 32
#define CIN   8
#define NCH   128   // 4*F_DIM
#define PP    128   // P

__device__ __forceinline__ float bf2f(unsigned short u) {
    union { unsigned int i; float f; } x; x.i = ((unsigned int)u) << 16; return x.f;
}
__device__ __forceinline__ unsigned short f2bf(float f) {
    union { float f; unsigned int i; } x; x.f = f;
    unsigned int r = x.i + 0x7fffu + ((x.i >> 16) & 1u);
    return (unsigned short)(r >> 16);
}

// ---------------------------------------------------------------------------
// K1: row sums RS1[b][c][p] (sum over q), col sums CS1[b][c][q] (sum over p)
// of t = relu(W1 @ phi + b1), computed on the fly. Grid: 32 b * 8 p-strips.
// ---------------------------------------------------------------------------
__global__ __launch_bounds__(256) void k1_sums(const float* __restrict__ phi,
        const float* __restrict__ W1, const float* __restrict__ b1,
        float* __restrict__ RS1, float* __restrict__ CS1) {
    int blk = blockIdx.x;
    int b = blk >> 3, strip = blk & 7;
    int p0 = strip * 16;
    __shared__ float cs_l[128][129];   // pad 129: breaks 32-way bank conflict
    __shared__ float phi_l[8][128];
    __shared__ float rs_l[2][128];
    int tid = threadIdx.x;
    int c = tid >> 1, qh = tid & 1;
    for (int k = tid; k < 128 * 129; k += 256) (&cs_l[0][0])[k] = 0.f;
    float w[8];
    #pragma unroll
    for (int ci = 0; ci < 8; ++ci) w[ci] = W1[c * 8 + ci];
    float bias = b1[c];
    __syncthreads();
    for (int pp = 0; pp < 16; ++pp) {
        int p = p0 + pp;
        for (int k = tid; k < 1024; k += 256) {
            int ci = k >> 7, q = k & 127;
            phi_l[ci][q] = phi[((b * CIN + ci) * PP + p) * PP + q];
        }
        __syncthreads();
        float rs = 0.f;
        for (int jq = 0; jq < 64; ++jq) {
            int q = qh * 64 + jq;
            float t = bias;
            #pragma unroll
            for (int ci = 0; ci < 8; ++ci) t = fmaf(w[ci], phi_l[ci][q], t);
            t = fmaxf(t, 0.f);
            cs_l[c][q] += t;
            rs += t;
        }
        rs_l[qh][c] = rs;
        __syncthreads();
        if (tid < 128) RS1[(b * NCH + tid) * PP + p] = rs_l[0][tid] + rs_l[1][tid];
        __syncthreads();
    }
    // flush column-sum partials (coalesced atomic adds; CS1 zeroed by host)
    for (int k = 0; k < 64; ++k) {
        int idx = k * 256 + tid;
        int cc = idx >> 7, q = idx & 127;
        atomicAdd(&CS1[(b * NCH + cc) * PP + q], cs_l[cc][q]);
    }
}

// ---------------------------------------------------------------------------
// K1b: bias planes.
//  A[b][o][q] = sum_c W3[o][32+c]/3*CS1[32+c][q] - W3[o][96+c]/9*CS1[96+c][q]
//  B[b][o][p] = sum_c W3[o][64+c]/3*RS1[64+c][p] - W3[o][96+c]/9*RS1[96+c][p]
//  C[b][o]    = b3[o] + sum_c W3[o][96+c]/9 * S1[96+c]
// Grid: 32 blocks (one per b).
// ---------------------------------------------------------------------------
__global__ __launch_bounds__(256) void k1b_planes(const float* __restrict__ W3,
        const float* __restrict__ b3, const float* __restrict__ RS1,
        const float* __restrict__ CS1, float* __restrict__ Ap,
        float* __restrict__ Bq, float* __restrict__ Cc) {
    int b = blockIdx.x, tid = threadIdx.x;
    __shared__ float s1_l[128];
    __shared__ float cs_g[64][132];   // rows 0..31 -> ch 32+r ; 32..63 -> ch 96..127
    __shared__ float rs_g[64][132];   // rows r -> ch 64+r
    if (tid < 128) {
        float s = 0.f;
        for (int p = 0; p < 128; ++p) s += RS1[(b * NCH + tid) * PP + p];
        s1_l[tid] = s;
    }
    for (int k = tid; k < 64 * 128; k += 256) {
        int r = k >> 7, q = k & 127;
        int ch_c = (r < 32) ? (32 + r) : (64 + r);
        cs_g[r][q] = CS1[(b * NCH + ch_c) * PP + q];
        rs_g[r][q] = RS1[(b * NCH + (64 + r)) * PP + q];
    }
    __syncthreads();
    int o = tid >> 1, qh = tid & 1;
    {
        float wa[64];
        #pragma unroll
        for (int r = 0; r < 64; ++r)
            wa[r] = (r < 32) ? W3[o * NCH + 32 + r] * (1.f / 3.f)
                             : -W3[o * NCH + 64 + r] * (1.f / 9.f);
        for (int jq = 0; jq < 16; ++jq) {
            int q = qh * 64 + jq * 4;
            float4 a = {0.f, 0.f, 0.f, 0.f};
            #pragma unroll
            for (int r = 0; r < 64; ++r) {
                float4 cv = *(const float4*)&cs_g[r][q];
                a.x = fmaf(wa[r], cv.x, a.x);
                a.y = fmaf(wa[r], cv.y, a.y);
                a.z = fmaf(wa[r], cv.z, a.z);
                a.w = fmaf(wa[r], cv.w, a.w);
            }
            *(float4*)&Ap[(b * NCH + o) * PP + q] = a;
        }
    }
    {
        float wb[64];
        #pragma unroll
        for (int r = 0; r < 64; ++r)
            wb[r] = (r < 32) ? W3[o * NCH + 64 + r] * (1.f / 3.f)
                             : -W3[o * NCH + 64 + r] * (1.f / 9.f);
        for (int jp = 0; jp < 16; ++jp) {
            int p = qh * 64 + jp * 4;
            float4 a = {0.f, 0.f, 0.f, 0.f};
            #pragma unroll
            for (int r = 0; r < 64; ++r) {
                float4 rv = *(const float4*)&rs_g[r][p];
                a.x = fmaf(wb[r], rv.x, a.x);
                a.y = fmaf(wb[r], rv.y, a.y);
                a.z = fmaf(wb[r], rv.z, a.z);
                a.w = fmaf(wb[r], rv.w, a.w);
            }
            *(float4*)&Bq[(b * NCH + o) * PP + p] = a;
        }
    }
    if (tid < 128) {
        float cv = b3[tid];
        #pragma unroll
        for (int r = 0; r < 32; ++r)
            cv = fmaf(W3[tid * NCH + 96 + r] * (1.f / 9.f), s1_l[96 + r], cv);
        Cc[b * NCH + tid] = cv;
    }
}

// ---------------------------------------------------------------------------
// K2: the fused heavy kernel. One block per (b, p)-row (4096 blocks, 512 thr).
//  t[c][q]  = relu(b1[c] + W1[c] . phi[b,:,p,q])     (recomputed, cheap)
//  v[o][q]  = relu( sum_c W3'[o][c]*t[c][q] + A[b,o,q] + B[b,o,p] + C[b,o] )
//  v stored bf16, channel-major: v2[b][o][p][q].
// ---------------------------------------------------------------------------
__global__ __launch_bounds__(512) void k2_gemm(const float* __restrict__ phi,
        const float* __restrict__ W1, const float* __restrict__ b1,
        const float* __restrict__ W3,
        const float* __restrict__ Ap, const float* __restrict__ Bq,
        const float* __restrict__ Cc, unsigned short* __restrict__ v2) {
    int b = blockIdx.x >> 7, p = blockIdx.x & 127;
    __shared__ float w3p[128][132];   // scaled W3' [o][c], pad 132
    __shared__ float t_l[128][132];   // t [q(pixel)][c], pad 132; reused as v_l
    __shared__ float phi_l[8][128];
    int tid = threadIdx.x;
    for (int k = tid; k < 16384; k += 512) {
        int c = k & 127;
        float sc = (c < 32) ? 1.f : ((c < 96) ? (-1.f / 3.f) : (1.f / 9.f));
        w3p[k >> 7][c] = W3[k] * sc;
    }
    for (int k = tid; k < 1024; k += 512) {
        int ci = k >> 7, q = k & 127;
        phi_l[ci][q] = phi[((b * CIN + ci) * PP + p) * PP + q];
    }
    __syncthreads();
    // build t tile
    int c_t = tid & 127;
    float w1r[8];
    #pragma unroll
    for (int ci = 0; ci < 8; ++ci) w1r[ci] = W1[c_t * 8 + ci];
    float b1_t = b1[c_t];
    for (int k = tid; k < 16384; k += 512) {
        int pix = k >> 7;
        float t = b1_t;
        #pragma unroll
        for (int ci = 0; ci < 8; ++ci) t = fmaf(w1r[ci], phi_l[ci][pix], t);
        t_l[pix][c_t] = fmaxf(t, 0.f);
    }
    __syncthreads();
    // register-tiled f32 GEMM: wave w owns pixels w*16 + r*4 + i (r,i in 0..3);
    // thread computes outs o = s*16 + j (s in 0..7).  Strided so LDS reads are <=2-way.
    int l = tid & 63, wv = tid >> 6;
    int i = l >> 4, j = l & 15;
    float acc[4][8];
    #pragma unroll
    for (int r = 0; r < 4; ++r)
        #pragma unroll
        for (int s = 0; s < 8; ++s) acc[r][s] = 0.f;
    for (int c = 0; c < 128; c += 4) {
        float4 tq[4];
        #pragma unroll
        for (int r = 0; r < 4; ++r) tq[r] = *(const float4*)&t_l[wv * 16 + r * 4 + i][c];
        float4 wm[8];
        #pragma unroll
        for (int s = 0; s < 8; ++s) wm[s] = *(const float4*)&w3p[s * 16 + j][c];
        #pragma unroll
        for (int r = 0; r < 4; ++r)
            #pragma unroll
            for (int s = 0; s < 8; ++s) {
                acc[r][s] = fmaf(tq[r].x, wm[s].x, acc[r][s]);
                acc[r][s] = fmaf(tq[r].y, wm[s].y, acc[r][s]);
                acc[r][s] = fmaf(tq[r].z, wm[s].z, acc[r][s]);
                acc[r][s] = fmaf(tq[r].w, wm[s].w, acc[r][s]);
            }
    }
    __syncthreads();              // everyone done reading t_l -> reuse as v_l
    unsigned short* v_l = (unsigned short*)&t_l[0][0];   // [128][132] bf16
    float bc[8], ccv[8];
    #pragma unroll
    for (int s = 0; s < 8; ++s) {
        int o = s * 16 + j;
        bc[s]  = Bq[(b * NCH + o) * PP + p];
        ccv[s] = Cc[b * NCH + o];
    }
    #pragma unroll
    for (int r = 0; r < 4; ++r) {
        int q = wv * 16 + r * 4 + i;
        #pragma unroll
        for (int s = 0; s < 8; ++s) {
            int o = s * 16 + j;
            float v = acc[r][s] + Ap[(b * NCH + o) * PP + q] + bc[s] + ccv[s];
            v_l[o * 132 + q] = f2bf(fmaxf(v, 0.f));
        }
    }
    __syncthreads();
    for (int k = tid; k < 8192; k += 512) {
        int o = k >> 6, q2 = (k & 63) * 2;
        ushort2 u;
        u.x = v_l[o * 132 + q2];
        u.y = v_l[o * 132 + q2 + 1];
        *(ushort2*)&v2[((b * NCH + o) * PP + p) * PP + q2] = u;
    }
}

// ---------------------------------------------------------------------------
// K2b: per-(b,ch) row/col/total sums of v. One block per (b,ch).
// ---------------------------------------------------------------------------
__global__ __launch_bounds__(256) void k2b_vsums(const unsigned short* __restrict__ v2,
        float* __restrict__ RSv, float* __restrict__ CSv, float* __restrict__ Sv) {
    int b = blockIdx.x >> 7, ch = blockIdx.x & 127;
    __shared__ float v_l[128][129];
    __shared__ float rs_tmp[128];
    int tid = threadIdx.x;
    const unsigned short* src = v2 + (size_t)(b * NCH + ch) * 16384;
    for (int k = tid; k < 4096; k += 256) {
        ushort4 u = ((const ushort4*)src)[k];
        int p = k >> 5, q = (k & 31) * 4;
        v_l[p][q]     = bf2f(u.x);
        v_l[p][q + 1] = bf2f(u.y);
        v_l[p][q + 2] = bf2f(u.z);
        v_l[p][q + 3] = bf2f(u.w);
    }
    __syncthreads();
    if (tid < 128) {
        float rs = 0.f;
        for (int q = 0; q < 128; ++q) rs += v_l[tid][q];
        RSv[(b * NCH + ch) * PP + tid] = rs;
        rs_tmp[tid] = rs;
    } else {
        int q = tid - 128;
        float cs = 0.f;
        for (int p = 0; p < 128; ++p) cs += v_l[p][q];
        CSv[(b * NCH + ch) * PP + q] = cs;
    }
    __syncthreads();
    if (tid < 64) {
        float s = rs_tmp[tid] + rs_tmp[tid + 64];
        #pragma unroll
        for (int off = 32; off > 0; off >>= 1) s += __shfl_down(s, off);
        if (tid == 0) Sv[b * NCH + ch] = s;
    }
}

// ---------------------------------------------------------------------------
// K3: final postprocess, elementwise with sums; layouts already match (no
// transpose).  One block per (b,ch).
// ---------------------------------------------------------------------------
__global__ __launch_bounds__(256) void k3_out(const unsigned short* __restrict__ v2,
        const float* __restrict__ RSv, const float* __restrict__ CSv,
        const float* __restrict__ Sv, float* __restrict__ out) {
    int b = blockIdx.x >> 7, ch = blockIdx.x & 127;
    int g = ch >> 5;
    __shared__ float rs_l[128], cs_l[128];
    int tid = threadIdx.x;
    size_t base = (size_t)(b * NCH + ch) * 16384;
    if (tid < 128) {
        rs_l[tid] = RSv[(b * NCH + ch) * PP + tid];
        cs_l[tid] = CSv[(b * NCH + ch) * PP + tid];
    }
    float sv = Sv[b * NCH + ch];
    __syncthreads();
    const ushort4* src = (const ushort4*)(v2 + base);
    float4* dst = (float4*)(out + base);
    for (int k = tid; k < 4096; k += 256) {
        ushort4 u = src[k];
        int p = k >> 5, q = (k & 31) * 4;
        float vv[4] = {bf2f(u.x), bf2f(u.y), bf2f(u.z), bf2f(u.w)};
        float4 o4;
        float* po = &o4.x;
        #pragma unroll
        for (int e = 0; e < 4; ++e) {
            float v = vv[e];
            float r;
            if (g == 0)      r = v;
            else if (g == 1) r = (cs_l[q + e] - v) * (1.f / 3.f);
            else if (g == 2) r = (rs_l[p] - v) * (1.f / 3.f);
            else             r = (sv - rs_l[p] - cs_l[q + e] + v) * (1.f / 9.f);
            po[e] = r;
        }
        dst[k] = o4;
    }
}

// ---------------------------------------------------------------------------
extern "C" void kernel_launch(void* const* d_in, const int* in_sizes, int n_in,
                              void* d_out, int out_size, void* d_ws, size_t ws_size,
                              hipStream_t stream) {
    (void)in_sizes; (void)n_in; (void)out_size; (void)ws_size;
    const float* phi = (const float*)d_in[0];
    const float* W1  = (const float*)d_in[1];
    const float* b1  = (const float*)d_in[2];
    const float* W3  = (const float*)d_in[3];
    const float* b3  = (const float*)d_in[4];
    // d_in[5] = ex, unused (closed form: ex = ones - eye)
    float* out = (float*)d_out;

    char* ws = (char*)d_ws;
    unsigned short* v2 = (unsigned short*)ws;                  // 134,217,728 B (bf16 v)
    size_t off = (size_t)BATCH * NCH * PP * PP * 2;
    float* RS1 = (float*)(ws + off); off += (size_t)BATCH * NCH * PP * 4;
    float* CS1 = (float*)(ws + off); off += (size_t)BATCH * NCH * PP * 4;
    float* Ap  = (float*)(ws + off); off += (size_t)BATCH * NCH * PP * 4;
    float* Bq  = (float*)(ws + off); off += (size_t)BATCH * NCH * PP * 4;
    float* Cc  = (float*)(ws + off); off += (size_t)BATCH * NCH * 4;
    float* RSv = (float*)(ws + off); off += (size_t)BATCH * NCH * PP * 4;
    float* CSv = (float*)(ws + off); off += (size_t)BATCH * NCH * PP * 4;
    float* Sv  = (float*)(ws + off); off += (size_t)BATCH * NCH * 4;

    hipMemsetAsync(CS1, 0, (size_t)BATCH * NCH * PP * 4, stream);   // K1 accumulates atomically
    k1_sums<<<BATCH * 8, 256, 0, stream>>>(phi, W1, b1, RS1, CS1);
    k1b_planes<<<BATCH, 256, 0, stream>>>(W3, b3, RS1, CS1, Ap, Bq, Cc);
    k2_gemm<<<BATCH * PP, 512, 0, stream>>>(phi, W1, b1, W3, Ap, Bq, Cc, v2);
    k2b_vsums<<<BATCH * NCH, 256, 0, stream>>>(v2, RSv, CSv, Sv);
    k3_out<<<BATCH * NCH, 256, 0, stream>>>(v2, RSv, CSv, Sv, out);
}

// Round 3
// 302.117 us; speedup vs baseline: 2.3055x; 2.3055x over previous
//
#include <hip/hip_runtime.h>
#include <stdint.h>

#define BATCH 32
#define CIN   8
#define NCH   128   // 4*F_DIM
#define PP    128   // P

typedef __attribute__((ext_vector_type(8))) short    bf16x8;
typedef __attribute__((ext_vector_type(4))) float    f32x4;

__device__ __forceinline__ float bf2f(unsigned short u) {
    union { unsigned int i; float f; } x; x.i = ((unsigned int)u) << 16; return x.f;
}
__device__ __forceinline__ unsigned short f2bf(float f) {
    union { float f; unsigned int i; } x; x.f = f;
    unsigned int r = x.i + 0x7fffu + ((x.i >> 16) & 1u);
    return (unsigned short)(r >> 16);
}

// Swizzled byte offset into a [128 rows][128 bf16] LDS tile.
// XOR of row low bits into byte bits 4-6 -> conflict-free ds_read_b128 of
// column slices (16 lanes x 16 rows, quarter-wave covers all 8 16B slots).
#define SWZB(row, cb) (((row) << 8) + ((cb) ^ (((row) & 7) << 4)))

// ---------------------------------------------------------------------------
// K1: row sums RS1[b][c][p] (sum over q), col sums CS1[b][c][q] (sum over p)
// of t = relu(W1 @ phi + b1), computed on the fly. Grid: 32 b * 8 p-strips.
// ---------------------------------------------------------------------------
__global__ __launch_bounds__(256) void k1_sums(const float* __restrict__ phi,
        const float* __restrict__ W1, const float* __restrict__ b1,
        float* __restrict__ RS1, float* __restrict__ CS1) {
    int blk = blockIdx.x;
    int b = blk >> 3, strip = blk & 7;
    int p0 = strip * 16;
    __shared__ float cs_l[128][129];
    __shared__ float phi_l[8][128];
    __shared__ float rs_l[2][128];
    int tid = threadIdx.x;
    int c = tid >> 1, qh = tid & 1;
    for (int k = tid; k < 128 * 129; k += 256) (&cs_l[0][0])[k] = 0.f;
    float w[8];
    #pragma unroll
    for (int ci = 0; ci < 8; ++ci) w[ci] = W1[c * 8 + ci];
    float bias = b1[c];
    __syncthreads();
    for (int pp = 0; pp < 16; ++pp) {
        int p = p0 + pp;
        for (int k = tid; k < 1024; k += 256) {
            int ci = k >> 7, q = k & 127;
            phi_l[ci][q] = phi[((b * CIN + ci) * PP + p) * PP + q];
        }
        __syncthreads();
        float rs = 0.f;
        for (int jq = 0; jq < 64; ++jq) {
            int q = qh * 64 + jq;
            float t = bias;
            #pragma unroll
            for (int ci = 0; ci < 8; ++ci) t = fmaf(w[ci], phi_l[ci][q], t);
            t = fmaxf(t, 0.f);
            cs_l[c][q] += t;
            rs += t;
        }
        rs_l[qh][c] = rs;
        __syncthreads();
        if (tid < 128) RS1[(b * NCH + tid) * PP + p] = rs_l[0][tid] + rs_l[1][tid];
        __syncthreads();
    }
    for (int k = 0; k < 64; ++k) {
        int idx = k * 256 + tid;
        int cc = idx >> 7, q = idx & 127;
        atomicAdd(&CS1[(b * NCH + cc) * PP + q], cs_l[cc][q]);
    }
}

// ---------------------------------------------------------------------------
// K1b: bias planes + (block 0) W3' bf16 conversion.
//  A[b][o][q], B[b][o][p], C[b][o] as before.
//  W3bf[o][c] = bf16( W3[o][c] * sc(c) ), sc = {1, -1/3, -1/3, 1/9} per group.
// ---------------------------------------------------------------------------
__global__ __launch_bounds__(256) void k1b_planes(const float* __restrict__ W3,
        const float* __restrict__ b3, const float* __restrict__ RS1,
        const float* __restrict__ CS1, float* __restrict__ Ap,
        float* __restrict__ Bq, float* __restrict__ Cc,
        unsigned short* __restrict__ W3bf) {
    int b = blockIdx.x, tid = threadIdx.x;
    __shared__ float s1_l[128];
    __shared__ float cs_g[64][132];
    __shared__ float rs_g[64][132];
    if (tid < 128) {
        float s = 0.f;
        for (int p = 0; p < 128; ++p) s += RS1[(b * NCH + tid) * PP + p];
        s1_l[tid] = s;
    }
    for (int k = tid; k < 64 * 128; k += 256) {
        int r = k >> 7, q = k & 127;
        int ch_c = (r < 32) ? (32 + r) : (64 + r);
        cs_g[r][q] = CS1[(b * NCH + ch_c) * PP + q];
        rs_g[r][q] = RS1[(b * NCH + (64 + r)) * PP + q];
    }
    __syncthreads();
    int o = tid >> 1, qh = tid & 1;
    {
        float wa[64];
        #pragma unroll
        for (int r = 0; r < 64; ++r)
            wa[r] = (r < 32) ? W3[o * NCH + 32 + r] * (1.f / 3.f)
                             : -W3[o * NCH + 64 + r] * (1.f / 9.f);
        for (int jq = 0; jq < 16; ++jq) {
            int q = qh * 64 + jq * 4;
            float4 a = {0.f, 0.f, 0.f, 0.f};
            #pragma unroll
            for (int r = 0; r < 64; ++r) {
                float4 cv = *(const float4*)&cs_g[r][q];
                a.x = fmaf(wa[r], cv.x, a.x);
                a.y = fmaf(wa[r], cv.y, a.y);
                a.z = fmaf(wa[r], cv.z, a.z);
                a.w = fmaf(wa[r], cv.w, a.w);
            }
            *(float4*)&Ap[(b * NCH + o) * PP + q] = a;
        }
    }
    {
        float wb[64];
        #pragma unroll
        for (int r = 0; r < 64; ++r)
            wb[r] = (r < 32) ? W3[o * NCH + 64 + r] * (1.f / 3.f)
                             : -W3[o * NCH + 64 + r] * (1.f / 9.f);
        for (int jp = 0; jp < 16; ++jp) {
            int p = qh * 64 + jp * 4;
            float4 a = {0.f, 0.f, 0.f, 0.f};
            #pragma unroll
            for (int r = 0; r < 64; ++r) {
                float4 rv = *(const float4*)&rs_g[r][p];
                a.x = fmaf(wb[r], rv.x, a.x);
                a.y = fmaf(wb[r], rv.y, a.y);
                a.z = fmaf(wb[r], rv.z, a.z);
                a.w = fmaf(wb[r], rv.w, a.w);
            }
            *(float4*)&Bq[(b * NCH + o) * PP + p] = a;
        }
    }
    if (tid < 128) {
        float cv = b3[tid];
        #pragma unroll
        for (int r = 0; r < 32; ++r)
            cv = fmaf(W3[tid * NCH + 96 + r] * (1.f / 9.f), s1_l[96 + r], cv);
        Cc[b * NCH + tid] = cv;
    }
    if (b == 0) {
        // convert W3 -> scaled bf16, linear [o][c]
        for (int i = 0; i < 16; ++i) {
            int k = tid + i * 256;        // float4 index
            float4 w = *(const float4*)(W3 + k * 4);
            int c0 = (k * 4) & 127;       // group boundary multiples of 4 -> uniform scale
            float sc = (c0 < 32) ? 1.f : ((c0 < 96) ? (-1.f / 3.f) : (1.f / 9.f));
            unsigned int lo = (unsigned int)f2bf(w.x * sc) | ((unsigned int)f2bf(w.y * sc) << 16);
            unsigned int hi = (unsigned int)f2bf(w.z * sc) | ((unsigned int)f2bf(w.w * sc) << 16);
            uint2 u = {lo, hi};
            *(uint2*)(W3bf + k * 4) = u;
        }
    }
}

// ---------------------------------------------------------------------------
// K2: MFMA version. One block per (b,p) row, 256 threads = 4 waves.
//  t[q][c] = relu(b1 + W1.phi)  (bf16, swizzled LDS)
//  v[q][o] = relu( t @ W3'^T + Ap[o][q] + Bq[o][p] + Cc[o] )  via
//  mfma_f32_16x16x32_bf16, acc initialized with the affine planes.
//  v stored bf16 channel-major v2[b][o][p][q].
// ---------------------------------------------------------------------------
__global__ __launch_bounds__(256) void k2_mfma(const float* __restrict__ phi,
        const float* __restrict__ W1, const float* __restrict__ b1,
        const unsigned short* __restrict__ W3bf,
        const float* __restrict__ Ap, const float* __restrict__ Bq,
        const float* __restrict__ Cc, unsigned short* __restrict__ v2) {
    int b = blockIdx.x >> 7, p = blockIdx.x & 127;
    __shared__ unsigned short w3_l[16384];   // [o][c] bf16 swizzled, 32 KB
    __shared__ unsigned short t_l[16384];    // [q][c] bf16 swizzled, 32 KB; reused as v_l[o][q]
    __shared__ float phi_l[8][128];
    __shared__ float BC_l[128];
    int tid = threadIdx.x;

    // stage W3' (bf16) -> LDS swizzled
    #pragma unroll
    for (int i = 0; i < 8; ++i) {
        int k = tid + i * 256;              // ushort8 index
        int o = k >> 4, cb = (k & 15) * 16;
        bf16x8 v = *(const bf16x8*)(W3bf + k * 8);
        *(bf16x8*)((char*)w3_l + SWZB(o, cb)) = v;
    }
    // stage phi row
    for (int k = tid; k < 1024; k += 256) {
        int ci = k >> 7, q = k & 127;
        phi_l[ci][q] = phi[((b * CIN + ci) * PP + p) * PP + q];
    }
    if (tid < 128) BC_l[tid] = Bq[(b * NCH + tid) * PP + p] + Cc[b * NCH + tid];
    __syncthreads();

    // build t tile: c fixed per thread
    int c_t = tid & 127;
    float w1r[8];
    #pragma unroll
    for (int ci = 0; ci < 8; ++ci) w1r[ci] = W1[c_t * 8 + ci];
    float b1t = b1[c_t];
    int pbase = tid >> 7;
    #pragma unroll 4
    for (int i = 0; i < 64; ++i) {
        int pix = pbase + i * 2;
        float t = b1t;
        #pragma unroll
        for (int ci = 0; ci < 8; ++ci) t = fmaf(w1r[ci], phi_l[ci][pix], t);
        *(unsigned short*)((char*)t_l + SWZB(pix, c_t * 2)) = f2bf(fmaxf(t, 0.f));
    }
    __syncthreads();

    // MFMA GEMM: wave wv owns q-tiles {2wv, 2wv+1} x all 8 o-tiles
    int wv = tid >> 6, l = tid & 63;
    int lr = l & 15, lg = l >> 4;
    bf16x8 afr[2][4];
    #pragma unroll
    for (int m = 0; m < 2; ++m) {
        int q = (wv * 2 + m) * 16 + lr;
        #pragma unroll
        for (int ks = 0; ks < 4; ++ks)
            afr[m][ks] = *(const bf16x8*)((char*)t_l + SWZB(q, ks * 64 + lg * 16));
    }
    f32x4 acc[2][8];
    #pragma unroll
    for (int nt = 0; nt < 8; ++nt) {
        int o = nt * 16 + lr;
        float bc = BC_l[o];
        #pragma unroll
        for (int m = 0; m < 2; ++m) {
            int q0 = (wv * 2 + m) * 16 + lg * 4;
            f32x4 ap = *(const f32x4*)(Ap + ((size_t)(b * NCH + o)) * PP + q0);
            acc[m][nt] = ap + bc;
        }
    }
    #pragma unroll
    for (int nt = 0; nt < 8; ++nt) {
        int o = nt * 16 + lr;
        bf16x8 bfr[4];
        #pragma unroll
        for (int ks = 0; ks < 4; ++ks)
            bfr[ks] = *(const bf16x8*)((char*)w3_l + SWZB(o, ks * 64 + lg * 16));
        #pragma unroll
        for (int m = 0; m < 2; ++m)
            #pragma unroll
            for (int ks = 0; ks < 4; ++ks)
                acc[m][nt] = __builtin_amdgcn_mfma_f32_16x16x32_bf16(
                                 afr[m][ks], bfr[ks], acc[m][nt], 0, 0, 0);
    }
    __syncthreads();                 // t_l dead -> reuse as v_l[o][q] (swizzled)
    unsigned short* v_l = t_l;
    #pragma unroll
    for (int m = 0; m < 2; ++m) {
        int q0 = (wv * 2 + m) * 16 + lg * 4;
        #pragma unroll
        for (int nt = 0; nt < 8; ++nt) {
            int o = nt * 16 + lr;
            f32x4 a = acc[m][nt];
            unsigned int lo = (unsigned int)f2bf(fmaxf(a.x, 0.f))
                            | ((unsigned int)f2bf(fmaxf(a.y, 0.f)) << 16);
            unsigned int hi = (unsigned int)f2bf(fmaxf(a.z, 0.f))
                            | ((unsigned int)f2bf(fmaxf(a.w, 0.f)) << 16);
            uint2 u = {lo, hi};
            *(uint2*)((char*)v_l + SWZB(o, q0 * 2)) = u;
        }
    }
    __syncthreads();
    // store v_l -> v2 (coalesced 16B per lane)
    #pragma unroll
    for (int i = 0; i < 8; ++i) {
        int k = tid + i * 256;
        int o = k >> 4, cb = (k & 15) * 16;
        bf16x8 v = *(const bf16x8*)((char*)v_l + SWZB(o, cb));
        *(bf16x8*)(v2 + ((size_t)(b * NCH + o) * PP + p) * PP + (k & 15) * 8) = v;
    }
}

// ---------------------------------------------------------------------------
// K3: merged sums + postprocess. One block per (b,ch); stages the 128x128
// bf16 plane, computes row/col/total sums in LDS, writes final output.
// ---------------------------------------------------------------------------
__global__ __launch_bounds__(256) void k3_out(const unsigned short* __restrict__ v2,
        float* __restrict__ out) {
    int b = blockIdx.x >> 7, ch = blockIdx.x & 127;
    int g = ch >> 5;
    __shared__ unsigned short v_l[128 * 136];   // pad stride 136 shorts (272 B)
    __shared__ float rs_l[128], cs_l[128];
    __shared__ float s_sh;
    int tid = threadIdx.x;
    size_t base = (size_t)(b * NCH + ch) * (PP * PP);
    const unsigned short* src = v2 + base;
    #pragma unroll
    for (int i = 0; i < 8; ++i) {
        int k = tid + i * 256;
        int pr = k >> 4, c8 = k & 15;
        *(bf16x8*)(v_l + pr * 136 + c8 * 8) = *(const bf16x8*)(src + k * 8);
    }
    __syncthreads();
    if (tid < 128) {
        float s = 0.f;
        #pragma unroll 4
        for (int j = 0; j < 16; ++j) {
            bf16x8 u = *(const bf16x8*)(v_l + tid * 136 + j * 8);
            #pragma unroll
            for (int e = 0; e < 8; ++e) s += bf2f((unsigned short)u[e]);
        }
        rs_l[tid] = s;
    } else {
        int q = tid - 128;
        float s = 0.f;
        for (int pr = 0; pr < 128; ++pr) s += bf2f(v_l[pr * 136 + q]);
        cs_l[q] = s;
    }
    __syncthreads();
    if (tid < 64) {
        float s = rs_l[tid] + rs_l[tid + 64];
        #pragma unroll
        for (int off = 32; off > 0; off >>= 1) s += __shfl_down(s, off);
        if (tid == 0) s_sh = s;
    }
    __syncthreads();
    float stot = s_sh;
    float* dst = out + base;
    #pragma unroll
    for (int i = 0; i < 8; ++i) {
        int k = tid + i * 256;
        int pr = k >> 4, q0 = (k & 15) * 8;
        bf16x8 u = *(const bf16x8*)(v_l + pr * 136 + q0);
        float rp = rs_l[pr];
        float o8[8];
        #pragma unroll
        for (int e = 0; e < 8; ++e) {
            float v = bf2f((unsigned short)u[e]);
            float cq = cs_l[q0 + e];
            float r;
            if (g == 0)      r = v;
            else if (g == 1) r = (cq - v) * (1.f / 3.f);
            else if (g == 2) r = (rp - v) * (1.f / 3.f);
            else             r = (stot - rp - cq + v) * (1.f / 9.f);
            o8[e] = r;
        }
        float4 lo = {o8[0], o8[1], o8[2], o8[3]};
        float4 hi = {o8[4], o8[5], o8[6], o8[7]};
        *(float4*)(dst + pr * 128 + q0)     = lo;
        *(float4*)(dst + pr * 128 + q0 + 4) = hi;
    }
}

// ---------------------------------------------------------------------------
extern "C" void kernel_launch(void* const* d_in, const int* in_sizes, int n_in,
                              void* d_out, int out_size, void* d_ws, size_t ws_size,
                              hipStream_t stream) {
    (void)in_sizes; (void)n_in; (void)out_size; (void)ws_size;
    const float* phi = (const float*)d_in[0];
    const float* W1  = (const float*)d_in[1];
    const float* b1  = (const float*)d_in[2];
    const float* W3  = (const float*)d_in[3];
    const float* b3  = (const float*)d_in[4];
    float* out = (float*)d_out;

    char* ws = (char*)d_ws;
    unsigned short* v2 = (unsigned short*)ws;                  // 134 MB bf16 v
    size_t off = (size_t)BATCH * NCH * PP * PP * 2;
    float* RS1 = (float*)(ws + off); off += (size_t)BATCH * NCH * PP * 4;
    float* CS1 = (float*)(ws + off); off += (size_t)BATCH * NCH * PP * 4;
    float* Ap  = (float*)(ws + off); off += (size_t)BATCH * NCH * PP * 4;
    float* Bq  = (float*)(ws + off); off += (size_t)BATCH * NCH * PP * 4;
    float* Cc  = (float*)(ws + off); off += (size_t)BATCH * NCH * 4;
    unsigned short* W3bf = (unsigned short*)(ws + off); off += (size_t)NCH * NCH * 2;

    hipMemsetAsync(CS1, 0, (size_t)BATCH * NCH * PP * 4, stream);
    k1_sums<<<BATCH * 8, 256, 0, stream>>>(phi, W1, b1, RS1, CS1);
    k1b_planes<<<BATCH, 256, 0, stream>>>(W3, b3, RS1, CS1, Ap, Bq, Cc, W3bf);
    k2_mfma<<<BATCH * PP, 256, 0, stream>>>(phi, W1, b1, W3bf, Ap, Bq, Cc, v2);
    k3_out<<<BATCH * NCH, 256, 0, stream>>>(v2, out);
}

// Round 4
// 232.077 us; speedup vs baseline: 3.0013x; 1.3018x over previous
//
#include <hip/hip_runtime.h>
#include <stdint.h>

#define BATCH 32
#define CIN   8
#define NCH   128   // 4*F_DIM
#define PP    128   // P
#define VCH   96    // channels kept in v2 (ch 32..127)

typedef __attribute__((ext_vector_type(8))) short    bf16x8;
typedef __attribute__((ext_vector_type(4))) float    f32x4;

__device__ __forceinline__ float bf2f(unsigned short u) {
    union { unsigned int i; float f; } x; x.i = ((unsigned int)u) << 16; return x.f;
}
__device__ __forceinline__ unsigned short f2bf(float f) {
    union { float f; unsigned int i; } x; x.f = f;
    unsigned int r = x.i + 0x7fffu + ((x.i >> 16) & 1u);
    return (unsigned short)(r >> 16);
}

// Swizzled byte offset into a [128 rows][128 bf16] LDS tile (row = 256 B).
#define SWZB(row, cb) (((row) << 8) + ((cb) ^ (((row) & 7) << 4)))

// ---------------------------------------------------------------------------
// K1: RS1t[b][p][c] = sum_q t, CS1[b][c][q] = sum_p t, t = relu(W1.phi + b1).
// Grid: 32 b x 16 strips (8 p each) = 512 blocks, 512 threads.
// Thread (c = tid&127, qq = tid>>7) accumulates col-sums for 32 q in REGISTERS.
// phi reads are wave-uniform float4 broadcasts from LDS.
// ---------------------------------------------------------------------------
__global__ __launch_bounds__(512) void k1_sums(const float* __restrict__ phi,
        const float* __restrict__ W1, const float* __restrict__ b1,
        float* __restrict__ RS1t, float* __restrict__ CS1) {
    __shared__ float S[17408];           // 69.6 KB: phi_s(8192) / cs_full(16896) overlay + rs_part(512)
    float* phi_s   = S;                  // [pi][ci][q] (dead before cs_full use)
    float* cs_full = S;                  // [128][132]
    float* rs_part = S + 16896;          // [128][4]
    int bx = blockIdx.x;
    int b = bx >> 4, strip = bx & 15;
    int p0 = strip * 8;
    int tid = threadIdx.x;
    int c = tid & 127, qq = tid >> 7;

    for (int k = tid; k < 8192; k += 512) {
        int pi = k >> 10, ci = (k >> 7) & 7, q = k & 127;
        phi_s[k] = phi[((b * CIN + ci) * PP + p0 + pi) * PP + q];
    }
    float4 w1a = *(const float4*)(W1 + c * 8);
    float4 w1b = *(const float4*)(W1 + c * 8 + 4);
    float b1c = b1[c];
    float cs_acc[32];
    #pragma unroll
    for (int j = 0; j < 32; ++j) cs_acc[j] = 0.f;
    __syncthreads();

    for (int pi = 0; pi < 8; ++pi) {
        float rsp = 0.f;
        const float* pb = phi_s + pi * 1024;
        #pragma unroll
        for (int j4 = 0; j4 < 8; ++j4) {
            int q4 = qq * 32 + j4 * 4;
            float4 ph[8];
            #pragma unroll
            for (int ci = 0; ci < 8; ++ci)
                ph[ci] = *(const float4*)(pb + ci * 128 + q4);
            #pragma unroll
            for (int e = 0; e < 4; ++e) {
                float t = b1c;
                t = fmaf(w1a.x, ((const float*)&ph[0])[e], t);
                t = fmaf(w1a.y, ((const float*)&ph[1])[e], t);
                t = fmaf(w1a.z, ((const float*)&ph[2])[e], t);
                t = fmaf(w1a.w, ((const float*)&ph[3])[e], t);
                t = fmaf(w1b.x, ((const float*)&ph[4])[e], t);
                t = fmaf(w1b.y, ((const float*)&ph[5])[e], t);
                t = fmaf(w1b.z, ((const float*)&ph[6])[e], t);
                t = fmaf(w1b.w, ((const float*)&ph[7])[e], t);
                t = fmaxf(t, 0.f);
                cs_acc[j4 * 4 + e] += t;
                rsp += t;
            }
        }
        rs_part[c * 4 + qq] = rsp;
        __syncthreads();
        if (tid < 128) {
            float4 r4 = *(const float4*)(rs_part + tid * 4);
            RS1t[(b * PP + p0 + pi) * NCH + tid] = r4.x + r4.y + r4.z + r4.w;
        }
        __syncthreads();
    }
    // flush register col-sums -> LDS (phi_s dead) -> coalesced atomicAdd
    #pragma unroll
    for (int j4 = 0; j4 < 8; ++j4) {
        float4 v = {cs_acc[j4 * 4], cs_acc[j4 * 4 + 1], cs_acc[j4 * 4 + 2], cs_acc[j4 * 4 + 3]};
        *(float4*)(cs_full + c * 132 + qq * 32 + j4 * 4) = v;
    }
    __syncthreads();
    for (int k = tid; k < 16384; k += 512) {
        int cc = k >> 7, q = k & 127;
        atomicAdd(&CS1[(b * NCH + cc) * PP + q], cs_full[cc * 132 + q]);
    }
}

// ---------------------------------------------------------------------------
// K1b: bias planes A/B/C + (block 0) scaled-bf16 W3.  RS1 is transposed (RS1t).
// ---------------------------------------------------------------------------
__global__ __launch_bounds__(256) void k1b_planes(const float* __restrict__ W3,
        const float* __restrict__ b3, const float* __restrict__ RS1t,
        const float* __restrict__ CS1, float* __restrict__ Ap,
        float* __restrict__ Bq, float* __restrict__ Cc,
        unsigned short* __restrict__ W3bf) {
    int b = blockIdx.x, tid = threadIdx.x;
    __shared__ float s1_l[128];
    __shared__ float cs_g[64][132];
    __shared__ float rs_g[64][132];
    if (tid < 128) {
        float s = 0.f;
        for (int p = 0; p < 128; ++p) s += RS1t[(b * PP + p) * NCH + tid];  // coalesced
        s1_l[tid] = s;
    }
    for (int k = tid; k < 64 * 128; k += 256) {
        int r = k >> 7, q = k & 127;
        int ch_c = (r < 32) ? (32 + r) : (64 + r);
        cs_g[r][q] = CS1[(b * NCH + ch_c) * PP + q];
    }
    for (int k = tid; k < 64 * 128; k += 256) {
        int p = k >> 6, r = k & 63;
        rs_g[r][p] = RS1t[(b * PP + p) * NCH + 64 + r];                     // coalesced
    }
    __syncthreads();
    int o = tid >> 1, qh = tid & 1;
    {
        float wa[64];
        #pragma unroll
        for (int r = 0; r < 64; ++r)
            wa[r] = (r < 32) ? W3[o * NCH + 32 + r] * (1.f / 3.f)
                             : -W3[o * NCH + 64 + r] * (1.f / 9.f);
        for (int jq = 0; jq < 16; ++jq) {
            int q = qh * 64 + jq * 4;
            float4 a = {0.f, 0.f, 0.f, 0.f};
            #pragma unroll
            for (int r = 0; r < 64; ++r) {
                float4 cv = *(const float4*)&cs_g[r][q];
                a.x = fmaf(wa[r], cv.x, a.x);
                a.y = fmaf(wa[r], cv.y, a.y);
                a.z = fmaf(wa[r], cv.z, a.z);
                a.w = fmaf(wa[r], cv.w, a.w);
            }
            *(float4*)&Ap[(b * NCH + o) * PP + q] = a;
        }
    }
    {
        float wb[64];
        #pragma unroll
        for (int r = 0; r < 64; ++r)
            wb[r] = (r < 32) ? W3[o * NCH + 64 + r] * (1.f / 3.f)
                             : -W3[o * NCH + 64 + r] * (1.f / 9.f);
        for (int jp = 0; jp < 16; ++jp) {
            int p = qh * 64 + jp * 4;
            float4 a = {0.f, 0.f, 0.f, 0.f};
            #pragma unroll
            for (int r = 0; r < 64; ++r) {
                float4 rv = *(const float4*)&rs_g[r][p];
                a.x = fmaf(wb[r], rv.x, a.x);
                a.y = fmaf(wb[r], rv.y, a.y);
                a.z = fmaf(wb[r], rv.z, a.z);
                a.w = fmaf(wb[r], rv.w, a.w);
            }
            *(float4*)&Bq[(b * NCH + o) * PP + p] = a;
        }
    }
    if (tid < 128) {
        float cv = b3[tid];
        #pragma unroll
        for (int r = 0; r < 32; ++r)
            cv = fmaf(W3[tid * NCH + 96 + r] * (1.f / 9.f), s1_l[96 + r], cv);
        Cc[b * NCH + tid] = cv;
    }
    if (b == 0) {
        for (int i = 0; i < 16; ++i) {
            int k = tid + i * 256;
            float4 w = *(const float4*)(W3 + k * 4);
            int c0 = (k * 4) & 127;
            float sc = (c0 < 32) ? 1.f : ((c0 < 96) ? (-1.f / 3.f) : (1.f / 9.f));
            unsigned int lo = (unsigned int)f2bf(w.x * sc) | ((unsigned int)f2bf(w.y * sc) << 16);
            unsigned int hi = (unsigned int)f2bf(w.z * sc) | ((unsigned int)f2bf(w.w * sc) << 16);
            uint2 u = {lo, hi};
            *(uint2*)(W3bf + k * 4) = u;
        }
    }
}

// ---------------------------------------------------------------------------
// K2: MFMA GEMM per (b,p) row.  g0 channels (o<32) -> out directly (f32);
// o>=32 -> v2 bf16 (96-channel compact layout).
// ---------------------------------------------------------------------------
__global__ __launch_bounds__(256) void k2_mfma(const float* __restrict__ phi,
        const float* __restrict__ W1, const float* __restrict__ b1,
        const unsigned short* __restrict__ W3bf,
        const float* __restrict__ Ap, const float* __restrict__ Bq,
        const float* __restrict__ Cc, float* __restrict__ out,
        unsigned short* __restrict__ v2) {
    int b = blockIdx.x >> 7, p = blockIdx.x & 127;
    __shared__ unsigned short w3_l[16384];   // [o][c] bf16 swizzled
    __shared__ unsigned short t_l[16384];    // [q][c] bf16 swizzled; reused as v_l[o][q]
    __shared__ float phi_l[8][128];
    __shared__ float BC_l[128];
    int tid = threadIdx.x;

    #pragma unroll
    for (int i = 0; i < 8; ++i) {
        int k = tid + i * 256;
        int o = k >> 4, cb = (k & 15) * 16;
        bf16x8 v = *(const bf16x8*)(W3bf + k * 8);
        *(bf16x8*)((char*)w3_l + SWZB(o, cb)) = v;
    }
    for (int k = tid; k < 1024; k += 256) {
        int ci = k >> 7, q = k & 127;
        phi_l[ci][q] = phi[((b * CIN + ci) * PP + p) * PP + q];
    }
    if (tid < 128) BC_l[tid] = Bq[(b * NCH + tid) * PP + p] + Cc[b * NCH + tid];
    __syncthreads();

    // t-build: thread (c_t, pg) computes 64 pixels, float4 phi broadcasts
    int c_t = tid & 127;
    int pg  = tid >> 7;
    float4 w1a = *(const float4*)(W1 + c_t * 8);
    float4 w1b = *(const float4*)(W1 + c_t * 8 + 4);
    float b1t = b1[c_t];
    #pragma unroll 4
    for (int i4 = 0; i4 < 16; ++i4) {
        int pix = pg * 64 + i4 * 4;
        float4 ph[8];
        #pragma unroll
        for (int ci = 0; ci < 8; ++ci)
            ph[ci] = *(const float4*)&phi_l[ci][pix];
        #pragma unroll
        for (int e = 0; e < 4; ++e) {
            float t = b1t;
            t = fmaf(w1a.x, ((const float*)&ph[0])[e], t);
            t = fmaf(w1a.y, ((const float*)&ph[1])[e], t);
            t = fmaf(w1a.z, ((const float*)&ph[2])[e], t);
            t = fmaf(w1a.w, ((const float*)&ph[3])[e], t);
            t = fmaf(w1b.x, ((const float*)&ph[4])[e], t);
            t = fmaf(w1b.y, ((const float*)&ph[5])[e], t);
            t = fmaf(w1b.z, ((const float*)&ph[6])[e], t);
            t = fmaf(w1b.w, ((const float*)&ph[7])[e], t);
            *(unsigned short*)((char*)t_l + SWZB(pix + e, c_t * 2)) = f2bf(fmaxf(t, 0.f));
        }
    }
    __syncthreads();

    int wv = tid >> 6, l = tid & 63;
    int lr = l & 15, lg = l >> 4;
    bf16x8 afr[2][4];
    #pragma unroll
    for (int m = 0; m < 2; ++m) {
        int q = (wv * 2 + m) * 16 + lr;
        #pragma unroll
        for (int ks = 0; ks < 4; ++ks)
            afr[m][ks] = *(const bf16x8*)((char*)t_l + SWZB(q, ks * 64 + lg * 16));
    }
    f32x4 acc[2][8];
    #pragma unroll
    for (int nt = 0; nt < 8; ++nt) {
        int o = nt * 16 + lr;
        float bc = BC_l[o];
        #pragma unroll
        for (int m = 0; m < 2; ++m) {
            int q0 = (wv * 2 + m) * 16 + lg * 4;
            f32x4 ap = *(const f32x4*)(Ap + ((size_t)(b * NCH + o)) * PP + q0);
            acc[m][nt] = ap + bc;
        }
    }
    #pragma unroll
    for (int nt = 0; nt < 8; ++nt) {
        int o = nt * 16 + lr;
        bf16x8 bfr[4];
        #pragma unroll
        for (int ks = 0; ks < 4; ++ks)
            bfr[ks] = *(const bf16x8*)((char*)w3_l + SWZB(o, ks * 64 + lg * 16));
        #pragma unroll
        for (int m = 0; m < 2; ++m)
            #pragma unroll
            for (int ks = 0; ks < 4; ++ks)
                acc[m][nt] = __builtin_amdgcn_mfma_f32_16x16x32_bf16(
                                 afr[m][ks], bfr[ks], acc[m][nt], 0, 0, 0);
    }
    __syncthreads();                 // t_l dead -> reuse as v_l
    unsigned short* v_l = t_l;
    // o < 32: relu + direct f32 store to out
    #pragma unroll
    for (int nt = 0; nt < 2; ++nt) {
        int o = nt * 16 + lr;
        #pragma unroll
        for (int m = 0; m < 2; ++m) {
            int q0 = (wv * 2 + m) * 16 + lg * 4;
            f32x4 a = acc[m][nt];
            f32x4 r = {fmaxf(a.x, 0.f), fmaxf(a.y, 0.f), fmaxf(a.z, 0.f), fmaxf(a.w, 0.f)};
            *(f32x4*)(out + ((size_t)((b * NCH + o) * PP + p)) * PP + q0) = r;
        }
    }
    // o >= 32: bf16 to v_l
    #pragma unroll
    for (int m = 0; m < 2; ++m) {
        int q0 = (wv * 2 + m) * 16 + lg * 4;
        #pragma unroll
        for (int nt = 2; nt < 8; ++nt) {
            int o = nt * 16 + lr;
            f32x4 a = acc[m][nt];
            unsigned int lo = (unsigned int)f2bf(fmaxf(a.x, 0.f))
                            | ((unsigned int)f2bf(fmaxf(a.y, 0.f)) << 16);
            unsigned int hi = (unsigned int)f2bf(fmaxf(a.z, 0.f))
                            | ((unsigned int)f2bf(fmaxf(a.w, 0.f)) << 16);
            uint2 u = {lo, hi};
            *(uint2*)((char*)v_l + SWZB(o, q0 * 2)) = u;
        }
    }
    __syncthreads();
    #pragma unroll
    for (int i = 0; i < 6; ++i) {
        int k = tid + i * 256;               // 1536 chunks = 96 rows x 16
        int o = 32 + (k >> 4), j = k & 15;
        bf16x8 v = *(const bf16x8*)((char*)v_l + SWZB(o, j * 16));
        *(bf16x8*)(v2 + ((size_t)(b * VCH + (o - 32)) * PP + p) * PP + j * 8) = v;
    }
}

// ---------------------------------------------------------------------------
// K3: sums + postprocess for ch 32..127.  Two global passes, lean LDS.
// Grid: 32 x 96 blocks, 256 threads.
// ---------------------------------------------------------------------------
__global__ __launch_bounds__(256) void k3_out(const unsigned short* __restrict__ v2,
        float* __restrict__ out) {
    int bx = blockIdx.x;
    int b = bx / VCH, cr = bx - b * VCH;
    int ch = 32 + cr;
    int g = ch >> 5;                          // 1,2,3
    __shared__ float rsp[128][16];
    __shared__ float csp[16][128];
    __shared__ float rs_l[128], cs_l[128];
    __shared__ float s_sh;
    int tid = threadIdx.x;
    const unsigned short* src = v2 + (size_t)(b * VCH + cr) * (PP * PP);

    // pass 1: sums
    int pc = tid >> 4, qc = tid & 15;
    float cs8[8];
    #pragma unroll
    for (int e = 0; e < 8; ++e) cs8[e] = 0.f;
    #pragma unroll
    for (int i = 0; i < 8; ++i) {
        int pr = pc * 8 + i;
        bf16x8 u = *(const bf16x8*)(src + pr * PP + qc * 8);
        float rp = 0.f;
        #pragma unroll
        for (int e = 0; e < 8; ++e) {
            float v = bf2f((unsigned short)u[e]);
            cs8[e] += v;
            rp += v;
        }
        rsp[pr][qc] = rp;
    }
    f32x4 clo = {cs8[0], cs8[1], cs8[2], cs8[3]};
    f32x4 chi = {cs8[4], cs8[5], cs8[6], cs8[7]};
    *(f32x4*)&csp[pc][qc * 8]     = clo;
    *(f32x4*)&csp[pc][qc * 8 + 4] = chi;
    __syncthreads();
    if (tid < 128) {
        f32x4 a = *(const f32x4*)&rsp[tid][0];
        f32x4 c2 = *(const f32x4*)&rsp[tid][4];
        f32x4 c3 = *(const f32x4*)&rsp[tid][8];
        f32x4 c4 = *(const f32x4*)&rsp[tid][12];
        rs_l[tid] = (a.x + a.y + a.z + a.w) + (c2.x + c2.y + c2.z + c2.w)
                  + (c3.x + c3.y + c3.z + c3.w) + (c4.x + c4.y + c4.z + c4.w);
    } else {
        int q = tid - 128;
        float s = 0.f;
        #pragma unroll
        for (int i = 0; i < 16; ++i) s += csp[i][q];
        cs_l[q] = s;
    }
    __syncthreads();
    if (tid < 64) {
        float s = rs_l[tid] + rs_l[tid + 64];
        #pragma unroll
        for (int off = 32; off > 0; off >>= 1) s += __shfl_down(s, off);
        if (tid == 0) s_sh = s;
    }
    __syncthreads();
    float stot = s_sh;

    // pass 2: output (plane re-read is L2-hot)
    float* dst = out + (size_t)(b * NCH + ch) * (PP * PP);
    #pragma unroll
    for (int i = 0; i < 8; ++i) {
        int k = tid + i * 256;
        int pr = k >> 4, q0 = (k & 15) * 8;
        bf16x8 u = *(const bf16x8*)(src + pr * PP + q0);
        float rp = rs_l[pr];
        float o8[8];
        #pragma unroll
        for (int e = 0; e < 8; ++e) {
            float v = bf2f((unsigned short)u[e]);
            float cq = cs_l[q0 + e];
            float r;
            if (g == 1)      r = (cq - v) * (1.f / 3.f);
            else if (g == 2) r = (rp - v) * (1.f / 3.f);
            else             r = (stot - rp - cq + v) * (1.f / 9.f);
            o8[e] = r;
        }
        f32x4 lo = {o8[0], o8[1], o8[2], o8[3]};
        f32x4 hi = {o8[4], o8[5], o8[6], o8[7]};
        *(f32x4*)(dst + pr * PP + q0)     = lo;
        *(f32x4*)(dst + pr * PP + q0 + 4) = hi;
    }
}

// ---------------------------------------------------------------------------
extern "C" void kernel_launch(void* const* d_in, const int* in_sizes, int n_in,
                              void* d_out, int out_size, void* d_ws, size_t ws_size,
                              hipStream_t stream) {
    (void)in_sizes; (void)n_in; (void)out_size; (void)ws_size;
    const float* phi = (const float*)d_in[0];
    const float* W1  = (const float*)d_in[1];
    const float* b1  = (const float*)d_in[2];
    const float* W3  = (const float*)d_in[3];
    const float* b3  = (const float*)d_in[4];
    float* out = (float*)d_out;

    char* ws = (char*)d_ws;
    unsigned short* v2 = (unsigned short*)ws;                  // 100.7 MB (96-ch bf16 v)
    size_t off = (size_t)BATCH * VCH * PP * PP * 2;
    float* RS1t = (float*)(ws + off); off += (size_t)BATCH * NCH * PP * 4;
    float* CS1  = (float*)(ws + off); off += (size_t)BATCH * NCH * PP * 4;
    float* Ap   = (float*)(ws + off); off += (size_t)BATCH * NCH * PP * 4;
    float* Bq   = (float*)(ws + off); off += (size_t)BATCH * NCH * PP * 4;
    float* Cc   = (float*)(ws + off); off += (size_t)BATCH * NCH * 4;
    unsigned short* W3bf = (unsigned short*)(ws + off); off += (size_t)NCH * NCH * 2;

    hipMemsetAsync(CS1, 0, (size_t)BATCH * NCH * PP * 4, stream);
    k1_sums<<<BATCH * 16, 512, 0, stream>>>(phi, W1, b1, RS1t, CS1);
    k1b_planes<<<BATCH, 256, 0, stream>>>(W3, b3, RS1t, CS1, Ap, Bq, Cc, W3bf);
    k2_mfma<<<BATCH * PP, 256, 0, stream>>>(phi, W1, b1, W3bf, Ap, Bq, Cc, out, v2);
    k3_out<<<BATCH * VCH, 256, 0, stream>>>(v2, out);
}

// Round 5
// 224.514 us; speedup vs baseline: 3.1024x; 1.0337x over previous
//
#include <hip/hip_runtime.h>
#include <stdint.h>

#define BATCH 32
#define CIN   8
#define NCH   128   // 4*F_DIM
#define PP    128   // P
#define VCH   96    // channels kept in v2 (ch 32..127)
#define NSTRIP 8    // k1 strips per batch (16 p each)

typedef __attribute__((ext_vector_type(8))) short    bf16x8;
typedef __attribute__((ext_vector_type(4))) float    f32x4;

__device__ __forceinline__ float bf2f(unsigned short u) {
    union { unsigned int i; float f; } x; x.i = ((unsigned int)u) << 16; return x.f;
}
__device__ __forceinline__ unsigned short f2bf(float f) {
    union { float f; unsigned int i; } x; x.f = f;
    unsigned int r = x.i + 0x7fffu + ((x.i >> 16) & 1u);
    return (unsigned short)(r >> 16);
}

// Swizzled byte offset into a [128 rows][128 bf16] LDS tile (row = 256 B).
#define SWZB(row, cb) (((row) << 8) + ((cb) ^ (((row) & 7) << 4)))

// ---------------------------------------------------------------------------
// K1: RS1t[b][p][c] = sum_q t ; CS1p[b][strip][c][q] = partial sum_p t
// (strip-partial, NO atomics, NO memset needed).  t = relu(W1.phi + b1).
// Grid: 32 b x 8 strips (16 p each) = 256 blocks, 512 threads.
// ---------------------------------------------------------------------------
__global__ __launch_bounds__(512) void k1_sums(const float* __restrict__ phi,
        const float* __restrict__ W1, const float* __restrict__ b1,
        float* __restrict__ RS1t, float* __restrict__ CS1p) {
    __shared__ float S[17408];           // phi_s(16384) / cs_full(16896) overlay + rs_part(512)
    float* phi_s   = S;                  // [pi][ci][q]
    float* cs_full = S;                  // [128][132]
    float* rs_part = S + 16896;          // [128][4]
    int bx = blockIdx.x;
    int b = bx >> 3, strip = bx & 7;
    int p0 = strip * 16;
    int tid = threadIdx.x;
    int c = tid & 127, qq = tid >> 7;

    for (int k = tid; k < 16384; k += 512) {
        int pi = k >> 10, ci = (k >> 7) & 7, q = k & 127;
        phi_s[k] = phi[((b * CIN + ci) * PP + p0 + pi) * PP + q];
    }
    float4 w1a = *(const float4*)(W1 + c * 8);
    float4 w1b = *(const float4*)(W1 + c * 8 + 4);
    float b1c = b1[c];
    float cs_acc[32];
    #pragma unroll
    for (int j = 0; j < 32; ++j) cs_acc[j] = 0.f;
    __syncthreads();

    for (int pi = 0; pi < 16; ++pi) {
        float rsp = 0.f;
        const float* pb = phi_s + pi * 1024;
        #pragma unroll
        for (int j4 = 0; j4 < 8; ++j4) {
            int q4 = qq * 32 + j4 * 4;
            float4 ph[8];
            #pragma unroll
            for (int ci = 0; ci < 8; ++ci)
                ph[ci] = *(const float4*)(pb + ci * 128 + q4);
            #pragma unroll
            for (int e = 0; e < 4; ++e) {
                float t = b1c;
                t = fmaf(w1a.x, ((const float*)&ph[0])[e], t);
                t = fmaf(w1a.y, ((const float*)&ph[1])[e], t);
                t = fmaf(w1a.z, ((const float*)&ph[2])[e], t);
                t = fmaf(w1a.w, ((const float*)&ph[3])[e], t);
                t = fmaf(w1b.x, ((const float*)&ph[4])[e], t);
                t = fmaf(w1b.y, ((const float*)&ph[5])[e], t);
                t = fmaf(w1b.z, ((const float*)&ph[6])[e], t);
                t = fmaf(w1b.w, ((const float*)&ph[7])[e], t);
                t = fmaxf(t, 0.f);
                cs_acc[j4 * 4 + e] += t;
                rsp += t;
            }
        }
        rs_part[c * 4 + qq] = rsp;
        __syncthreads();
        if (tid < 128) {
            float4 r4 = *(const float4*)(rs_part + tid * 4);
            RS1t[(b * PP + p0 + pi) * NCH + tid] = r4.x + r4.y + r4.z + r4.w;
        }
        __syncthreads();
    }
    // flush register col-sums -> LDS (phi_s dead) -> plain coalesced store
    #pragma unroll
    for (int j4 = 0; j4 < 8; ++j4) {
        float4 v = {cs_acc[j4 * 4], cs_acc[j4 * 4 + 1], cs_acc[j4 * 4 + 2], cs_acc[j4 * 4 + 3]};
        *(float4*)(cs_full + c * 132 + qq * 32 + j4 * 4) = v;
    }
    __syncthreads();
    float* dstp = CS1p + (size_t)(b * NSTRIP + strip) * NCH * PP;
    for (int k = tid; k < 16384; k += 512) {
        int cc = k >> 7, q = k & 127;
        dstp[k] = cs_full[cc * 132 + q];
    }
}

// ---------------------------------------------------------------------------
// K1b: bias planes A/B/C + W3/W1 bf16 conversion.  Grid: 32 b x 4 o-groups.
// cs_g staged with 8-strip reduction of CS1p.
// ---------------------------------------------------------------------------
__global__ __launch_bounds__(256) void k1b_planes(const float* __restrict__ W3,
        const float* __restrict__ b3, const float* __restrict__ RS1t,
        const float* __restrict__ CS1p, float* __restrict__ Ap,
        float* __restrict__ Bq, float* __restrict__ Cc,
        unsigned short* __restrict__ W3bf) {
    int bx = blockIdx.x;
    int b = bx >> 2, og = bx & 3;
    int tid = threadIdx.x;
    __shared__ float cs_g[64][132];   // rows 0..31 -> ch 32+r ; 32..63 -> ch 96..127
    __shared__ float rs_g[64][132];   // rows r -> ch 64+r
    __shared__ float s1_96[32];
    for (int k = tid; k < 64 * 128; k += 256) {
        int r = k >> 7, q = k & 127;
        int ch_c = (r < 32) ? (32 + r) : (64 + r);
        float s = 0.f;
        #pragma unroll
        for (int s8 = 0; s8 < NSTRIP; ++s8)
            s += CS1p[((size_t)(b * NSTRIP + s8) * NCH + ch_c) * PP + q];
        cs_g[r][q] = s;
    }
    for (int k = tid; k < 64 * 128; k += 256) {
        int p = k >> 6, r = k & 63;
        rs_g[r][p] = RS1t[(b * PP + p) * NCH + 64 + r];
    }
    __syncthreads();
    if (og == 0 && tid < 32) {        // s1[96+r] = sum_q CS[96+r][q] = sum_q cs_g[32+r][q]
        float s = 0.f;
        for (int q = 0; q < 128; ++q) s += cs_g[32 + tid][q];
        s1_96[tid] = s;
    }
    int o = og * 32 + (tid >> 3), qh = tid & 7;
    {
        float wa[64];
        #pragma unroll
        for (int r = 0; r < 64; ++r)
            wa[r] = (r < 32) ? W3[o * NCH + 32 + r] * (1.f / 3.f)
                             : -W3[o * NCH + 64 + r] * (1.f / 9.f);
        #pragma unroll
        for (int j = 0; j < 4; ++j) {
            int q = qh * 16 + j * 4;
            float4 a = {0.f, 0.f, 0.f, 0.f};
            #pragma unroll
            for (int r = 0; r < 64; ++r) {
                float4 cv = *(const float4*)&cs_g[r][q];
                a.x = fmaf(wa[r], cv.x, a.x);
                a.y = fmaf(wa[r], cv.y, a.y);
                a.z = fmaf(wa[r], cv.z, a.z);
                a.w = fmaf(wa[r], cv.w, a.w);
            }
            *(float4*)&Ap[(b * NCH + o) * PP + q] = a;
        }
    }
    {
        float wb[64];
        #pragma unroll
        for (int r = 0; r < 64; ++r)
            wb[r] = (r < 32) ? W3[o * NCH + 64 + r] * (1.f / 3.f)
                             : -W3[o * NCH + 64 + r] * (1.f / 9.f);
        #pragma unroll
        for (int j = 0; j < 4; ++j) {
            int p = qh * 16 + j * 4;
            float4 a = {0.f, 0.f, 0.f, 0.f};
            #pragma unroll
            for (int r = 0; r < 64; ++r) {
                float4 rv = *(const float4*)&rs_g[r][p];
                a.x = fmaf(wb[r], rv.x, a.x);
                a.y = fmaf(wb[r], rv.y, a.y);
                a.z = fmaf(wb[r], rv.z, a.z);
                a.w = fmaf(wb[r], rv.w, a.w);
            }
            *(float4*)&Bq[(b * NCH + o) * PP + p] = a;
        }
    }
    __syncthreads();
    if (og == 0 && tid < 128) {
        float cv = b3[tid];
        #pragma unroll
        for (int r = 0; r < 32; ++r)
            cv = fmaf(W3[tid * NCH + 96 + r] * (1.f / 9.f), s1_96[r], cv);
        Cc[b * NCH + tid] = cv;
    }
    if (bx == 0) {
        for (int i = 0; i < 16; ++i) {
            int k = tid + i * 256;
            float4 w = *(const float4*)(W3 + k * 4);
            int c0 = (k * 4) & 127;
            float sc = (c0 < 32) ? 1.f : ((c0 < 96) ? (-1.f / 3.f) : (1.f / 9.f));
            unsigned int lo = (unsigned int)f2bf(w.x * sc) | ((unsigned int)f2bf(w.y * sc) << 16);
            unsigned int hi = (unsigned int)f2bf(w.z * sc) | ((unsigned int)f2bf(w.w * sc) << 16);
            uint2 u = {lo, hi};
            *(uint2*)(W3bf + k * 4) = u;
        }
    }
}

// ---------------------------------------------------------------------------
// K2: per (b,p) row.  Stage phi & W1 as bf16 (K padded to 32 with zeros),
// t = relu(W1.phi + b1) via MFMA (operands swapped: lane holds 4 consecutive
// c -> single ds_write_b64 into swizzled t_l), then v-GEMM via MFMA.
// g0 (o<32) -> out f32 directly; o>=32 -> v2 bf16.
// ---------------------------------------------------------------------------
__global__ __launch_bounds__(256) void k2_mfma(const float* __restrict__ phi,
        const float* __restrict__ W1, const float* __restrict__ b1,
        const unsigned short* __restrict__ W3bf,
        const float* __restrict__ Ap, const float* __restrict__ Bq,
        const float* __restrict__ Cc, float* __restrict__ out,
        unsigned short* __restrict__ v2) {
    int b = blockIdx.x >> 7, p = blockIdx.x & 127;
    __shared__ unsigned short w3_l[16384];      // [o][c] bf16 swizzled
    __shared__ unsigned short t_l[16384];       // [pixel][c] bf16 swizzled; reused as v_l
    __shared__ unsigned short phi_b[128 * 36];  // [pixel][k] k<8 real, 8..31 zero
    __shared__ unsigned short w1_b[128 * 36];   // [c][k]
    __shared__ float BC_l[128];
    __shared__ float b1_l[128];
    int tid = threadIdx.x;

    // zero pad buffers (k>=8 region must be 0; simplest: zero everything)
    for (int k = tid; k < 2304; k += 256) {
        ((unsigned int*)phi_b)[k] = 0u;
        ((unsigned int*)w1_b)[k] = 0u;
    }
    // stage W3' bf16 -> swizzled LDS
    #pragma unroll
    for (int i = 0; i < 8; ++i) {
        int k = tid + i * 256;
        int o = k >> 4, cb = (k & 15) * 16;
        bf16x8 v = *(const bf16x8*)(W3bf + k * 8);
        *(bf16x8*)((char*)w3_l + SWZB(o, cb)) = v;
    }
    if (tid < 128) {
        BC_l[tid] = Bq[(b * NCH + tid) * PP + p] + Cc[b * NCH + tid];
        b1_l[tid] = b1[tid];
    }
    __syncthreads();
    // fill phi_b: phi row (b,:,p,:) -> [q][ci] bf16
    {
        int idx = tid * 4;                  // 1024 f32
        int ci = idx >> 7, q0 = idx & 127;
        float4 v = *(const float4*)(phi + ((size_t)(b * CIN + ci) * PP + p) * PP + q0);
        phi_b[(q0 + 0) * 36 + ci] = f2bf(v.x);
        phi_b[(q0 + 1) * 36 + ci] = f2bf(v.y);
        phi_b[(q0 + 2) * 36 + ci] = f2bf(v.z);
        phi_b[(q0 + 3) * 36 + ci] = f2bf(v.w);
    }
    // fill w1_b: [c][k<8]
    {
        int idx = tid * 4;                  // 1024 f32
        int c = idx >> 3, k0 = idx & 7;
        float4 v = *(const float4*)(W1 + c * 8 + k0);
        w1_b[c * 36 + k0 + 0] = f2bf(v.x);
        w1_b[c * 36 + k0 + 1] = f2bf(v.y);
        w1_b[c * 36 + k0 + 2] = f2bf(v.z);
        w1_b[c * 36 + k0 + 3] = f2bf(v.w);
    }
    __syncthreads();

    int wv = tid >> 6, l = tid & 63;
    int lr = l & 15, lg = l >> 4;

    // ---- GEMM1: t[c][pixel] tiles; wave owns ct in {2wv,2wv+1} x all 8 pt.
    // A = W1 rows (c), B = phi rows (pixel).  D: c = ct*16+lg*4+reg, pix = pt*16+lr.
    {
        bf16x8 afr1[2];
        f32x4 binit[2];
        #pragma unroll
        for (int i = 0; i < 2; ++i) {
            int ct = wv * 2 + i;
            afr1[i] = *(const bf16x8*)((char*)w1_b + (ct * 16 + lr) * 72 + lg * 16);
            int c0 = ct * 16 + lg * 4;
            f32x4 bi = {b1_l[c0], b1_l[c0 + 1], b1_l[c0 + 2], b1_l[c0 + 3]};
            binit[i] = bi;
        }
        #pragma unroll
        for (int pt = 0; pt < 8; ++pt) {
            int pix = pt * 16 + lr;
            bf16x8 bfr1 = *(const bf16x8*)((char*)phi_b + pix * 72 + lg * 16);
            #pragma unroll
            for (int i = 0; i < 2; ++i) {
                int c0 = (wv * 2 + i) * 16 + lg * 4;
                f32x4 a = __builtin_amdgcn_mfma_f32_16x16x32_bf16(afr1[i], bfr1, binit[i], 0, 0, 0);
                unsigned int lo = (unsigned int)f2bf(fmaxf(a.x, 0.f))
                                | ((unsigned int)f2bf(fmaxf(a.y, 0.f)) << 16);
                unsigned int hi = (unsigned int)f2bf(fmaxf(a.z, 0.f))
                                | ((unsigned int)f2bf(fmaxf(a.w, 0.f)) << 16);
                uint2 u = {lo, hi};
                *(uint2*)((char*)t_l + SWZB(pix, c0 * 2)) = u;
            }
        }
    }
    __syncthreads();

    // ---- GEMM2: v[q][o]; wave owns q-tiles {2wv,2wv+1} x all 8 o-tiles.
    bf16x8 afr[2][4];
    #pragma unroll
    for (int m = 0; m < 2; ++m) {
        int q = (wv * 2 + m) * 16 + lr;
        #pragma unroll
        for (int ks = 0; ks < 4; ++ks)
            afr[m][ks] = *(const bf16x8*)((char*)t_l + SWZB(q, ks * 64 + lg * 16));
    }
    f32x4 acc[2][8];
    #pragma unroll
    for (int nt = 0; nt < 8; ++nt) {
        int o = nt * 16 + lr;
        float bc = BC_l[o];
        #pragma unroll
        for (int m = 0; m < 2; ++m) {
            int q0 = (wv * 2 + m) * 16 + lg * 4;
            f32x4 ap = *(const f32x4*)(Ap + ((size_t)(b * NCH + o)) * PP + q0);
            acc[m][nt] = ap + bc;
        }
    }
    #pragma unroll
    for (int nt = 0; nt < 8; ++nt) {
        int o = nt * 16 + lr;
        bf16x8 bfr[4];
        #pragma unroll
        for (int ks = 0; ks < 4; ++ks)
            bfr[ks] = *(const bf16x8*)((char*)w3_l + SWZB(o, ks * 64 + lg * 16));
        #pragma unroll
        for (int m = 0; m < 2; ++m)
            #pragma unroll
            for (int ks = 0; ks < 4; ++ks)
                acc[m][nt] = __builtin_amdgcn_mfma_f32_16x16x32_bf16(
                                 afr[m][ks], bfr[ks], acc[m][nt], 0, 0, 0);
    }
    __syncthreads();                 // t_l dead -> reuse as v_l
    unsigned short* v_l = t_l;
    #pragma unroll
    for (int nt = 0; nt < 2; ++nt) {
        int o = nt * 16 + lr;
        #pragma unroll
        for (int m = 0; m < 2; ++m) {
            int q0 = (wv * 2 + m) * 16 + lg * 4;
            f32x4 a = acc[m][nt];
            f32x4 r = {fmaxf(a.x, 0.f), fmaxf(a.y, 0.f), fmaxf(a.z, 0.f), fmaxf(a.w, 0.f)};
            *(f32x4*)(out + ((size_t)((b * NCH + o) * PP + p)) * PP + q0) = r;
        }
    }
    #pragma unroll
    for (int m = 0; m < 2; ++m) {
        int q0 = (wv * 2 + m) * 16 + lg * 4;
        #pragma unroll
        for (int nt = 2; nt < 8; ++nt) {
            int o = nt * 16 + lr;
            f32x4 a = acc[m][nt];
            unsigned int lo = (unsigned int)f2bf(fmaxf(a.x, 0.f))
                            | ((unsigned int)f2bf(fmaxf(a.y, 0.f)) << 16);
            unsigned int hi = (unsigned int)f2bf(fmaxf(a.z, 0.f))
                            | ((unsigned int)f2bf(fmaxf(a.w, 0.f)) << 16);
            uint2 u = {lo, hi};
            *(uint2*)((char*)v_l + SWZB(o, q0 * 2)) = u;
        }
    }
    __syncthreads();
    #pragma unroll
    for (int i = 0; i < 6; ++i) {
        int k = tid + i * 256;               // 1536 chunks = 96 rows x 16
        int o = 32 + (k >> 4), j = k & 15;
        bf16x8 v = *(const bf16x8*)((char*)v_l + SWZB(o, j * 16));
        *(bf16x8*)(v2 + ((size_t)(b * VCH + (o - 32)) * PP + p) * PP + j * 8) = v;
    }
}

// ---------------------------------------------------------------------------
// K3: sums + postprocess for ch 32..127.  Two global passes (2nd L2-hot).
// ---------------------------------------------------------------------------
__global__ __launch_bounds__(256) void k3_out(const unsigned short* __restrict__ v2,
        float* __restrict__ out) {
    int bx = blockIdx.x;
    int b = bx / VCH, cr = bx - b * VCH;
    int ch = 32 + cr;
    int g = ch >> 5;                          // 1,2,3
    __shared__ float rsp[128][16];
    __shared__ float csp[16][128];
    __shared__ float rs_l[128], cs_l[128];
    __shared__ float s_sh;
    int tid = threadIdx.x;
    const unsigned short* src = v2 + (size_t)(b * VCH + cr) * (PP * PP);

    int pc = tid >> 4, qc = tid & 15;
    float cs8[8];
    #pragma unroll
    for (int e = 0; e < 8; ++e) cs8[e] = 0.f;
    #pragma unroll
    for (int i = 0; i < 8; ++i) {
        int pr = pc * 8 + i;
        bf16x8 u = *(const bf16x8*)(src + pr * PP + qc * 8);
        float rp = 0.f;
        #pragma unroll
        for (int e = 0; e < 8; ++e) {
            float v = bf2f((unsigned short)u[e]);
            cs8[e] += v;
            rp += v;
        }
        rsp[pr][qc] = rp;
    }
    f32x4 clo = {cs8[0], cs8[1], cs8[2], cs8[3]};
    f32x4 chi = {cs8[4], cs8[5], cs8[6], cs8[7]};
    *(f32x4*)&csp[pc][qc * 8]     = clo;
    *(f32x4*)&csp[pc][qc * 8 + 4] = chi;
    __syncthreads();
    if (tid < 128) {
        f32x4 a  = *(const f32x4*)&rsp[tid][0];
        f32x4 c2 = *(const f32x4*)&rsp[tid][4];
        f32x4 c3 = *(const f32x4*)&rsp[tid][8];
        f32x4 c4 = *(const f32x4*)&rsp[tid][12];
        rs_l[tid] = (a.x + a.y + a.z + a.w) + (c2.x + c2.y + c2.z + c2.w)
                  + (c3.x + c3.y + c3.z + c3.w) + (c4.x + c4.y + c4.z + c4.w);
    } else {
        int q = tid - 128;
        float s = 0.f;
        #pragma unroll
        for (int i = 0; i < 16; ++i) s += csp[i][q];
        cs_l[q] = s;
    }
    __syncthreads();
    if (tid < 64) {
        float s = rs_l[tid] + rs_l[tid + 64];
        #pragma unroll
        for (int off = 32; off > 0; off >>= 1) s += __shfl_down(s, off);
        if (tid == 0) s_sh = s;
    }
    __syncthreads();
    float stot = s_sh;

    float* dst = out + (size_t)(b * NCH + ch) * (PP * PP);
    #pragma unroll
    for (int i = 0; i < 8; ++i) {
        int k = tid + i * 256;
        int pr = k >> 4, q0 = (k & 15) * 8;
        bf16x8 u = *(const bf16x8*)(src + pr * PP + q0);
        float rp = rs_l[pr];
        float o8[8];
        #pragma unroll
        for (int e = 0; e < 8; ++e) {
            float v = bf2f((unsigned short)u[e]);
            float cq = cs_l[q0 + e];
            float r;
            if (g == 1)      r = (cq - v) * (1.f / 3.f);
            else if (g == 2) r = (rp - v) * (1.f / 3.f);
            else             r = (stot - rp - cq + v) * (1.f / 9.f);
            o8[e] = r;
        }
        f32x4 lo = {o8[0], o8[1], o8[2], o8[3]};
        f32x4 hi = {o8[4], o8[5], o8[6], o8[7]};
        *(f32x4*)(dst + pr * PP + q0)     = lo;
        *(f32x4*)(dst + pr * PP + q0 + 4) = hi;
    }
}

// ---------------------------------------------------------------------------
extern "C" void kernel_launch(void* const* d_in, const int* in_sizes, int n_in,
                              void* d_out, int out_size, void* d_ws, size_t ws_size,
                              hipStream_t stream) {
    (void)in_sizes; (void)n_in; (void)out_size; (void)ws_size;
    const float* phi = (const float*)d_in[0];
    const float* W1  = (const float*)d_in[1];
    const float* b1  = (const float*)d_in[2];
    const float* W3  = (const float*)d_in[3];
    const float* b3  = (const float*)d_in[4];
    float* out = (float*)d_out;

    char* ws = (char*)d_ws;
    unsigned short* v2 = (unsigned short*)ws;                  // 100.7 MB
    size_t off = (size_t)BATCH * VCH * PP * PP * 2;
    float* RS1t = (float*)(ws + off); off += (size_t)BATCH * NCH * PP * 4;
    float* CS1p = (float*)(ws + off); off += (size_t)BATCH * NSTRIP * NCH * PP * 4;
    float* Ap   = (float*)(ws + off); off += (size_t)BATCH * NCH * PP * 4;
    float* Bq   = (float*)(ws + off); off += (size_t)BATCH * NCH * PP * 4;
    float* Cc   = (float*)(ws + off); off += (size_t)BATCH * NCH * 4;
    unsigned short* W3bf = (unsigned short*)(ws + off); off += (size_t)NCH * NCH * 2;

    k1_sums<<<BATCH * NSTRIP, 512, 0, stream>>>(phi, W1, b1, RS1t, CS1p);
    k1b_planes<<<BATCH * 4, 256, 0, stream>>>(W3, b3, RS1t, CS1p, Ap, Bq, Cc, W3bf);
    k2_mfma<<<BATCH * PP, 256, 0, stream>>>(phi, W1, b1, W3bf, Ap, Bq, Cc, out, v2);
    k3_out<<<BATCH * VCH, 256, 0, stream>>>(v2, out);
}

// Round 6
// 207.430 us; speedup vs baseline: 3.3579x; 1.0824x over previous
//
#include <hip/hip_runtime.h>
#include <stdint.h>

#define BATCH 32
#define CIN   8
#define NCH   128   // 4*F_DIM
#define PP    128   // P
#define VCH   96    // channels kept in v2 (ch 32..127)
#define NSTRIP 8    // k1 strips per batch (16 p each)

typedef __attribute__((ext_vector_type(8))) short    bf16x8;
typedef __attribute__((ext_vector_type(4))) float    f32x4;

__device__ __forceinline__ float bf2f(unsigned short u) {
    union { unsigned int i; float f; } x; x.i = ((unsigned int)u) << 16; return x.f;
}
__device__ __forceinline__ unsigned short f2bf(float f) {
    union { float f; unsigned int i; } x; x.f = f;
    unsigned int r = x.i + 0x7fffu + ((x.i >> 16) & 1u);
    return (unsigned short)(r >> 16);
}
__device__ __forceinline__ unsigned int pk2(float a, float b) {
    return (unsigned int)f2bf(a) | ((unsigned int)f2bf(b) << 16);
}

// Swizzled byte offset into a [128 rows][128 bf16] LDS tile (row = 256 B).
#define SWZB(row, cb) (((row) << 8) + ((cb) ^ (((row) & 7) << 4)))

// ---------------------------------------------------------------------------
// K1: RS1t[b][p][c] = sum_q t ; CS1p[b][strip][c][q] = partial sum_p t.
// t = relu(W1.phi + b1).  Grid: 32 b x 8 strips (16 p each), 512 threads.
// Row sums kept in registers across the strip -> only 5 barriers total.
// ---------------------------------------------------------------------------
__global__ __launch_bounds__(512) void k1_sums(const float* __restrict__ phi,
        const float* __restrict__ W1, const float* __restrict__ b1,
        float* __restrict__ RS1t, float* __restrict__ CS1p) {
    __shared__ float S[17408];
    int bx = blockIdx.x;
    int b = bx >> 3, strip = bx & 7;
    int p0 = strip * 16;
    int tid = threadIdx.x;
    int c = tid & 127, qq = tid >> 7;

    // stage phi strip: [pi 16][ci 8][q 128]
    #pragma unroll
    for (int i = 0; i < 8; ++i) {
        int idx = tid + i * 512;                 // float4 index
        int pi = idx >> 8, ci = (idx >> 5) & 7, q4 = (idx & 31) * 4;
        float4 v = *(const float4*)(phi + ((size_t)(b * CIN + ci) * PP + p0 + pi) * PP + q4);
        *(float4*)(S + pi * 1024 + ci * 128 + q4) = v;
    }
    float4 w1a = *(const float4*)(W1 + c * 8);
    float4 w1b = *(const float4*)(W1 + c * 8 + 4);
    float b1c = b1[c];
    float cs_acc[32];
    #pragma unroll
    for (int j = 0; j < 32; ++j) cs_acc[j] = 0.f;
    float rsp[16];
    __syncthreads();

    for (int pi = 0; pi < 16; ++pi) {
        float rs = 0.f;
        const float* pb = S + pi * 1024;
        #pragma unroll
        for (int j4 = 0; j4 < 8; ++j4) {
            int q4 = qq * 32 + j4 * 4;
            float4 ph[8];
            #pragma unroll
            for (int ci = 0; ci < 8; ++ci)
                ph[ci] = *(const float4*)(pb + ci * 128 + q4);
            #pragma unroll
            for (int e = 0; e < 4; ++e) {
                float t = b1c;
                t = fmaf(w1a.x, ((const float*)&ph[0])[e], t);
                t = fmaf(w1a.y, ((const float*)&ph[1])[e], t);
                t = fmaf(w1a.z, ((const float*)&ph[2])[e], t);
                t = fmaf(w1a.w, ((const float*)&ph[3])[e], t);
                t = fmaf(w1b.x, ((const float*)&ph[4])[e], t);
                t = fmaf(w1b.y, ((const float*)&ph[5])[e], t);
                t = fmaf(w1b.z, ((const float*)&ph[6])[e], t);
                t = fmaf(w1b.w, ((const float*)&ph[7])[e], t);
                t = fmaxf(t, 0.f);
                cs_acc[j4 * 4 + e] += t;
                rs += t;
            }
        }
        rsp[pi] = rs;
    }
    __syncthreads();                 // phi_s dead
    // rs flush: S[pi*512 + qq*128 + c] = S[pi*512 + tid]
    #pragma unroll
    for (int pi = 0; pi < 16; ++pi) S[pi * 512 + tid] = rsp[pi];
    __syncthreads();
    #pragma unroll
    for (int i = 0; i < 4; ++i) {
        int idx = tid + i * 512;
        int pi = idx >> 7, cc = idx & 127;
        float s = S[pi * 512 + cc] + S[pi * 512 + 128 + cc]
                + S[pi * 512 + 256 + cc] + S[pi * 512 + 384 + cc];
        RS1t[((size_t)b * PP + p0 + pi) * NCH + cc] = s;
    }
    __syncthreads();                 // rs region dead
    #pragma unroll
    for (int j4 = 0; j4 < 8; ++j4) {
        float4 v = {cs_acc[j4 * 4], cs_acc[j4 * 4 + 1], cs_acc[j4 * 4 + 2], cs_acc[j4 * 4 + 3]};
        *(float4*)(S + c * 132 + qq * 32 + j4 * 4) = v;
    }
    __syncthreads();
    float* dstp = CS1p + (size_t)(b * NSTRIP + strip) * NCH * PP;
    for (int k = tid; k < 16384; k += 512) {
        int cc = k >> 7, q = k & 127;
        dstp[k] = S[cc * 132 + q];
    }
}

// ---------------------------------------------------------------------------
// K1b: Ap[b][o][q], Bqt[b][p][o] (with Cc folded in), W3bf (block 0).
// Grid: 32 b x 4 o-groups, 256 threads.
// ---------------------------------------------------------------------------
__global__ __launch_bounds__(256) void k1b_planes(const float* __restrict__ W3,
        const float* __restrict__ b3, const float* __restrict__ RS1t,
        const float* __restrict__ CS1p, float* __restrict__ Ap,
        float* __restrict__ Bqt, unsigned short* __restrict__ W3bf) {
    int bx = blockIdx.x;
    int b = bx >> 2, og = bx & 3;
    int tid = threadIdx.x;
    __shared__ float cs_g[64][132];   // rows 0..31 -> ch 32+r ; 32..63 -> ch 96..127
    __shared__ float rs_g[64][132];   // rows r -> ch 64+r
    __shared__ float s1_96[32];
    for (int k = tid; k < 64 * 128; k += 256) {
        int r = k >> 7, q = k & 127;
        int ch_c = (r < 32) ? (32 + r) : (64 + r);
        float s = 0.f;
        #pragma unroll
        for (int s8 = 0; s8 < NSTRIP; ++s8)
            s += CS1p[((size_t)(b * NSTRIP + s8) * NCH + ch_c) * PP + q];
        cs_g[r][q] = s;
    }
    for (int k = tid; k < 64 * 128; k += 256) {
        int p = k >> 6, r = k & 63;
        rs_g[r][p] = RS1t[((size_t)b * PP + p) * NCH + 64 + r];
    }
    __syncthreads();
    if (tid < 32) {
        float s = 0.f;
        for (int q = 0; q < 128; ++q) s += cs_g[32 + tid][q];
        s1_96[tid] = s;
    }
    int o = og * 32 + (tid >> 3), qh = tid & 7;
    {
        float wa[64];
        #pragma unroll
        for (int r = 0; r < 64; ++r)
            wa[r] = (r < 32) ? W3[o * NCH + 32 + r] * (1.f / 3.f)
                             : -W3[o * NCH + 64 + r] * (1.f / 9.f);
        #pragma unroll
        for (int j = 0; j < 4; ++j) {
            int q = qh * 16 + j * 4;
            float4 a = {0.f, 0.f, 0.f, 0.f};
            #pragma unroll
            for (int r = 0; r < 64; ++r) {
                float4 cv = *(const float4*)&cs_g[r][q];
                a.x = fmaf(wa[r], cv.x, a.x);
                a.y = fmaf(wa[r], cv.y, a.y);
                a.z = fmaf(wa[r], cv.z, a.z);
                a.w = fmaf(wa[r], cv.w, a.w);
            }
            *(float4*)&Ap[((size_t)b * NCH + o) * PP + q] = a;
        }
    }
    __syncthreads();                 // s1_96 ready
    float cc = b3[o];
    #pragma unroll
    for (int r = 0; r < 32; ++r)
        cc = fmaf(W3[o * NCH + 96 + r] * (1.f / 9.f), s1_96[r], cc);
    {
        float wb[64];
        #pragma unroll
        for (int r = 0; r < 64; ++r)
            wb[r] = (r < 32) ? W3[o * NCH + 64 + r] * (1.f / 3.f)
                             : -W3[o * NCH + 64 + r] * (1.f / 9.f);
        #pragma unroll
        for (int j = 0; j < 4; ++j) {
            int p4 = qh * 16 + j * 4;
            float4 a = {0.f, 0.f, 0.f, 0.f};
            #pragma unroll
            for (int r = 0; r < 64; ++r) {
                float4 rv = *(const float4*)&rs_g[r][p4];
                a.x = fmaf(wb[r], rv.x, a.x);
                a.y = fmaf(wb[r], rv.y, a.y);
                a.z = fmaf(wb[r], rv.z, a.z);
                a.w = fmaf(wb[r], rv.w, a.w);
            }
            Bqt[((size_t)b * PP + p4 + 0) * NCH + o] = a.x + cc;
            Bqt[((size_t)b * PP + p4 + 1) * NCH + o] = a.y + cc;
            Bqt[((size_t)b * PP + p4 + 2) * NCH + o] = a.z + cc;
            Bqt[((size_t)b * PP + p4 + 3) * NCH + o] = a.w + cc;
        }
    }
    if (bx == 0) {
        for (int i = 0; i < 16; ++i) {
            int k = tid + i * 256;
            float4 w = *(const float4*)(W3 + k * 4);
            int c0 = (k * 4) & 127;
            float sc = (c0 < 32) ? 1.f : ((c0 < 96) ? (-1.f / 3.f) : (1.f / 9.f));
            unsigned int lo = pk2(w.x * sc, w.y * sc);
            unsigned int hi = pk2(w.z * sc, w.w * sc);
            uint2 u = {lo, hi};
            *(uint2*)(W3bf + k * 4) = u;
        }
    }
}

// ---------------------------------------------------------------------------
// K2: row-loop MFMA kernel.  Grid: 32 b x 16 strips (8 p-rows each) = 512
// blocks, 512 threads / 8 waves.  W3' staged once per block; per row:
// t = relu(W1.phi+b1) via MFMA (K=32, lanes lg>0 feed zero frags),
// v = t @ W3'^T + Ap + Bqt via MFMA; g0 -> out f32, rest -> v2 bf16.
// LDS 70.6 KB -> 2 blocks/CU (16 waves/CU).
// ---------------------------------------------------------------------------
__global__ __launch_bounds__(512, 4) void k2_mfma(const float* __restrict__ phi,
        const float* __restrict__ W1, const float* __restrict__ b1,
        const unsigned short* __restrict__ W3bf,
        const float* __restrict__ Ap, const float* __restrict__ Bqt,
        float* __restrict__ out, unsigned short* __restrict__ v2) {
    int bx = blockIdx.x;
    int b = bx >> 4, strip = bx & 15;
    int p0 = strip * 8;
    __shared__ unsigned short w3_l[16384];      // [o][c] bf16 swizzled, 32 KB
    __shared__ unsigned short t_l[16384];       // [pix][c] swizzled; reused as v_l[o][q]
    __shared__ unsigned short phi_b[2][1024];   // [pix][ci] bf16, 2 KB each
    __shared__ float BC_l[2][128];
    int tid = threadIdx.x;
    int wv = tid >> 6, l = tid & 63, lr = l & 15, lg = l >> 4;

    // stage W3' swizzled
    #pragma unroll
    for (int i = 0; i < 4; ++i) {
        int k = tid + i * 512;
        int o = k >> 4, cb = (k & 15) * 16;
        bf16x8 v = *(const bf16x8*)(W3bf + k * 8);
        *(bf16x8*)((char*)w3_l + SWZB(o, cb)) = v;
    }
    // W1 fragment in registers (lg==0 lanes hold the 8 real k, others zero)
    bf16x8 w1fr = {0, 0, 0, 0, 0, 0, 0, 0};
    if (lg == 0) {
        int cc = wv * 16 + lr;
        float4 wa = *(const float4*)(W1 + cc * 8);
        float4 wb = *(const float4*)(W1 + cc * 8 + 4);
        w1fr[0] = (short)f2bf(wa.x); w1fr[1] = (short)f2bf(wa.y);
        w1fr[2] = (short)f2bf(wa.z); w1fr[3] = (short)f2bf(wa.w);
        w1fr[4] = (short)f2bf(wb.x); w1fr[5] = (short)f2bf(wb.y);
        w1fr[6] = (short)f2bf(wb.z); w1fr[7] = (short)f2bf(wb.w);
    }
    int c0 = wv * 16 + lg * 4;
    f32x4 binit = {b1[c0], b1[c0 + 1], b1[c0 + 2], b1[c0 + 3]};
    // prologue: phi_b[0] + BC_l[0] for row p0
    if (tid < 128) {
        int q = tid;
        bf16x8 pv;
        #pragma unroll
        for (int ci = 0; ci < 8; ++ci)
            pv[ci] = (short)f2bf(phi[((size_t)(b * CIN + ci) * PP + p0) * PP + q]);
        *(bf16x8*)(phi_b[0] + q * 8) = pv;
        BC_l[0][tid] = Bqt[((size_t)b * PP + p0) * NCH + tid];
    }
    __syncthreads();

    for (int r = 0; r < 8; ++r) {
        int cur = r & 1, nxt = cur ^ 1;
        int p = p0 + r;
        // prefetch next row into registers
        float pfv[8]; float bcn = 0.f;
        if (r < 7 && tid < 128) {
            int q = tid;
            #pragma unroll
            for (int ci = 0; ci < 8; ++ci)
                pfv[ci] = phi[((size_t)(b * CIN + ci) * PP + p + 1) * PP + q];
            bcn = Bqt[((size_t)b * PP + p + 1) * NCH + tid];
        }
        // GEMM1: t[c][pix]; wave wv owns c-tile wv
        const unsigned short* pb = phi_b[cur];
        #pragma unroll
        for (int pt = 0; pt < 8; ++pt) {
            int pix = pt * 16 + lr;
            bf16x8 bfr1 = {0, 0, 0, 0, 0, 0, 0, 0};
            if (lg == 0) bfr1 = *(const bf16x8*)(pb + pix * 8);
            f32x4 a = __builtin_amdgcn_mfma_f32_16x16x32_bf16(w1fr, bfr1, binit, 0, 0, 0);
            uint2 u;
            u.x = pk2(fmaxf(a.x, 0.f), fmaxf(a.y, 0.f));
            u.y = pk2(fmaxf(a.z, 0.f), fmaxf(a.w, 0.f));
            *(uint2*)((char*)t_l + SWZB(pix, c0 * 2)) = u;
        }
        __syncthreads();
        // GEMM2: v[q][o]; wave wv owns q-tile wv x all 8 o-tiles
        bf16x8 afr[4];
        #pragma unroll
        for (int ks = 0; ks < 4; ++ks)
            afr[ks] = *(const bf16x8*)((char*)t_l + SWZB(wv * 16 + lr, ks * 64 + lg * 16));
        f32x4 acc[8];
        #pragma unroll
        for (int nt = 0; nt < 8; ++nt) {
            int o = nt * 16 + lr;
            f32x4 ap = *(const f32x4*)(Ap + ((size_t)(b * NCH + o)) * PP + wv * 16 + lg * 4);
            acc[nt] = ap + BC_l[cur][o];
        }
        #pragma unroll
        for (int nt = 0; nt < 8; ++nt) {
            int o = nt * 16 + lr;
            bf16x8 bfr[4];
            #pragma unroll
            for (int ks = 0; ks < 4; ++ks)
                bfr[ks] = *(const bf16x8*)((char*)w3_l + SWZB(o, ks * 64 + lg * 16));
            #pragma unroll
            for (int ks = 0; ks < 4; ++ks)
                acc[nt] = __builtin_amdgcn_mfma_f32_16x16x32_bf16(afr[ks], bfr[ks], acc[nt], 0, 0, 0);
        }
        __syncthreads();             // afr reads done -> t_l reusable as v_l
        // epilogue: g0 -> out, rest -> v_l
        #pragma unroll
        for (int nt = 0; nt < 2; ++nt) {
            int o = nt * 16 + lr;
            f32x4 a = acc[nt];
            f32x4 rr = {fmaxf(a.x, 0.f), fmaxf(a.y, 0.f), fmaxf(a.z, 0.f), fmaxf(a.w, 0.f)};
            *(f32x4*)(out + ((size_t)(b * NCH + o) * PP + p) * PP + wv * 16 + lg * 4) = rr;
        }
        #pragma unroll
        for (int nt = 2; nt < 8; ++nt) {
            int o = nt * 16 + lr;
            f32x4 a = acc[nt];
            uint2 u;
            u.x = pk2(fmaxf(a.x, 0.f), fmaxf(a.y, 0.f));
            u.y = pk2(fmaxf(a.z, 0.f), fmaxf(a.w, 0.f));
            *(uint2*)((char*)t_l + SWZB(o, (wv * 16 + lg * 4) * 2)) = u;
        }
        if (r < 7 && tid < 128) {
            bf16x8 pv;
            #pragma unroll
            for (int ci = 0; ci < 8; ++ci) pv[ci] = (short)f2bf(pfv[ci]);
            *(bf16x8*)(phi_b[nxt] + tid * 8) = pv;
            BC_l[nxt][tid] = bcn;
        }
        __syncthreads();             // v_l complete + next phi ready
        // v2 stores (coalesced 16B chunks)
        #pragma unroll
        for (int i = 0; i < 3; ++i) {
            int k = tid + i * 512;
            int o = 32 + (k >> 4), j = k & 15;
            bf16x8 v = *(const bf16x8*)((char*)t_l + SWZB(o, j * 16));
            *(bf16x8*)(v2 + ((size_t)(b * VCH + (o - 32)) * PP + p) * PP + j * 8) = v;
        }
        __syncthreads();             // v_l consumed before next GEMM1
    }
}

// ---------------------------------------------------------------------------
// K3: sums + postprocess for ch 32..127.  Two global passes (2nd L2-hot).
// ---------------------------------------------------------------------------
__global__ __launch_bounds__(256) void k3_out(const unsigned short* __restrict__ v2,
        float* __restrict__ out) {
    int bx = blockIdx.x;
    int b = bx / VCH, cr = bx - b * VCH;
    int ch = 32 + cr;
    int g = ch >> 5;                          // 1,2,3
    __shared__ float rsp[128][16];
    __shared__ float csp[16][128];
    __shared__ float rs_l[128], cs_l[128];
    __shared__ float s_sh;
    int tid = threadIdx.x;
    const unsigned short* src = v2 + (size_t)(b * VCH + cr) * (PP * PP);

    int pc = tid >> 4, qc = tid & 15;
    float cs8[8];
    #pragma unroll
    for (int e = 0; e < 8; ++e) cs8[e] = 0.f;
    #pragma unroll
    for (int i = 0; i < 8; ++i) {
        int pr = pc * 8 + i;
        bf16x8 u = *(const bf16x8*)(src + pr * PP + qc * 8);
        float rp = 0.f;
        #pragma unroll
        for (int e = 0; e < 8; ++e) {
            float v = bf2f((unsigned short)u[e]);
            cs8[e] += v;
            rp += v;
        }
        rsp[pr][qc] = rp;
    }
    f32x4 clo = {cs8[0], cs8[1], cs8[2], cs8[3]};
    f32x4 chi = {cs8[4], cs8[5], cs8[6], cs8[7]};
    *(f32x4*)&csp[pc][qc * 8]     = clo;
    *(f32x4*)&csp[pc][qc * 8 + 4] = chi;
    __syncthreads();
    if (tid < 128) {
        f32x4 a  = *(const f32x4*)&rsp[tid][0];
        f32x4 c2 = *(const f32x4*)&rsp[tid][4];
        f32x4 c3 = *(const f32x4*)&rsp[tid][8];
        f32x4 c4 = *(const f32x4*)&rsp[tid][12];
        rs_l[tid] = (a.x + a.y + a.z + a.w) + (c2.x + c2.y + c2.z + c2.w)
                  + (c3.x + c3.y + c3.z + c3.w) + (c4.x + c4.y + c4.z + c4.w);
    } else {
        int q = tid - 128;
        float s = 0.f;
        #pragma unroll
        for (int i = 0; i < 16; ++i) s += csp[i][q];
        cs_l[q] = s;
    }
    __syncthreads();
    if (tid < 64) {
        float s = rs_l[tid] + rs_l[tid + 64];
        #pragma unroll
        for (int off = 32; off > 0; off >>= 1) s += __shfl_down(s, off);
        if (tid == 0) s_sh = s;
    }
    __syncthreads();
    float stot = s_sh;

    float* dst = out + (size_t)(b * NCH + ch) * (PP * PP);
    #pragma unroll
    for (int i = 0; i < 8; ++i) {
        int k = tid + i * 256;
        int pr = k >> 4, q0 = (k & 15) * 8;
        bf16x8 u = *(const bf16x8*)(src + pr * PP + q0);
        float rp = rs_l[pr];
        float o8[8];
        #pragma unroll
        for (int e = 0; e < 8; ++e) {
            float v = bf2f((unsigned short)u[e]);
            float cq = cs_l[q0 + e];
            float r;
            if (g == 1)      r = (cq - v) * (1.f / 3.f);
            else if (g == 2) r = (rp - v) * (1.f / 3.f);
            else             r = (stot - rp - cq + v) * (1.f / 9.f);
            o8[e] = r;
        }
        f32x4 lo = {o8[0], o8[1], o8[2], o8[3]};
        f32x4 hi = {o8[4], o8[5], o8[6], o8[7]};
        *(f32x4*)(dst + pr * PP + q0)     = lo;
        *(f32x4*)(dst + pr * PP + q0 + 4) = hi;
    }
}

// ---------------------------------------------------------------------------
extern "C" void kernel_launch(void* const* d_in, const int* in_sizes, int n_in,
                              void* d_out, int out_size, void* d_ws, size_t ws_size,
                              hipStream_t stream) {
    (void)in_sizes; (void)n_in; (void)out_size; (void)ws_size;
    const float* phi = (const float*)d_in[0];
    const float* W1  = (const float*)d_in[1];
    const float* b1  = (const float*)d_in[2];
    const float* W3  = (const float*)d_in[3];
    const float* b3  = (const float*)d_in[4];
    float* out = (float*)d_out;

    char* ws = (char*)d_ws;
    unsigned short* v2 = (unsigned short*)ws;                  // 100.7 MB
    size_t off = (size_t)BATCH * VCH * PP * PP * 2;
    float* RS1t = (float*)(ws + off); off += (size_t)BATCH * NCH * PP * 4;
    float* CS1p = (float*)(ws + off); off += (size_t)BATCH * NSTRIP * NCH * PP * 4;
    float* Ap   = (float*)(ws + off); off += (size_t)BATCH * NCH * PP * 4;
    float* Bqt  = (float*)(ws + off); off += (size_t)BATCH * NCH * PP * 4;
    unsigned short* W3bf = (unsigned short*)(ws + off); off += (size_t)NCH * NCH * 2;

    k1_sums<<<BATCH * NSTRIP, 512, 0, stream>>>(phi, W1, b1, RS1t, CS1p);
    k1b_planes<<<BATCH * 4, 256, 0, stream>>>(W3, b3, RS1t, CS1p, Ap, Bqt, W3bf);
    k2_mfma<<<BATCH * 16, 512, 0, stream>>>(phi, W1, b1, W3bf, Ap, Bqt, out, v2);
    k3_out<<<BATCH * VCH, 256, 0, stream>>>(v2, out);
}